// Round 1
// baseline (388.184 us; speedup 1.0000x reference)
//
#include <hip/hip_runtime.h>
#include <cmath>

#define ROWS      16384
#define SEQLEN    8192
#define BATCH     2
#define NHEADS    24
#define HEADDIM   16
#define D_STATE   16
#define D_INNER   384
#define D_MODEL   192
#define D_IN_PROJ 808
#define CONV_DIM  400
#define NCHUNKS   32
#define CHUNK     256
#define EPS       1e-5f

__device__ __forceinline__ float silu_f(float x) { return x / (1.0f + expf(-x)); }
__device__ __forceinline__ float softplus_f(float x) { return (x > 20.0f) ? x : log1pf(expf(x)); }

// ---------------------------------------------------------------------------
// Generic tiled fp32 GEMM: C[M,N] = A[M,K] * W[N,K]^T   (both row-major)
// K must be a multiple of BK. M,N guarded.
// ---------------------------------------------------------------------------
template<int BM, int BN, int BK, int TM, int TN>
__launch_bounds__((BM / TM) * (BN / TN))
__global__ void gemm_nt(const float* __restrict__ A, const float* __restrict__ W,
                        float* __restrict__ C, int M, int N, int K) {
  __shared__ float As[BK][BM + 4];
  __shared__ float Ws[BK][BN + 4];
  constexpr int NTX = BN / TN;
  constexpr int NT  = (BM / TM) * (BN / TN);
  const int tid = threadIdx.x;
  const int tx  = tid % NTX;
  const int ty  = tid / NTX;
  const long m0 = (long)blockIdx.y * BM;
  const long n0 = (long)blockIdx.x * BN;
  float acc[TM][TN] = {};

  for (int k0 = 0; k0 < K; k0 += BK) {
    for (int i = tid; i < BM * BK; i += NT) {
      int m = i / BK, kk = i % BK;
      long gm = m0 + m;
      As[kk][m] = (gm < M) ? A[gm * K + (k0 + kk)] : 0.0f;
    }
    for (int i = tid; i < BN * BK; i += NT) {
      int n = i / BK, kk = i % BK;
      long gn = n0 + n;
      Ws[kk][n] = (gn < N) ? W[gn * K + (k0 + kk)] : 0.0f;
    }
    __syncthreads();
#pragma unroll
    for (int kk = 0; kk < BK; ++kk) {
      float a[TM], w[TN];
#pragma unroll
      for (int i = 0; i < TM; ++i) a[i] = As[kk][ty * TM + i];
#pragma unroll
      for (int j = 0; j < TN; ++j) w[j] = Ws[kk][tx * TN + j];
#pragma unroll
      for (int i = 0; i < TM; ++i)
#pragma unroll
        for (int j = 0; j < TN; ++j)
          acc[i][j] += a[i] * w[j];
    }
    __syncthreads();
  }
#pragma unroll
  for (int i = 0; i < TM; ++i) {
    long gm = m0 + ty * TM + i;
    if (gm >= M) continue;
#pragma unroll
    for (int j = 0; j < TN; ++j) {
      long gn = n0 + tx * TN + j;
      if (gn < N) C[gm * N + gn] = acc[i][j];
    }
  }
}

// ---------------------------------------------------------------------------
// K2: depthwise causal conv (width 4) + silu for xB (400 ch) and C (16 ch),
//     plus dt = softplus(zxbdt[...,-24:] + dt_bias).
// One block per (b,t) row, 448 threads.
// ---------------------------------------------------------------------------
__global__ __launch_bounds__(448)
void conv_dt_kernel(const float* __restrict__ zxbdt, const float* __restrict__ cproj,
                    const float* __restrict__ conv_w, const float* __restrict__ conv_b,
                    const float* __restrict__ conv_w_b, const float* __restrict__ conv_b_b,
                    const float* __restrict__ dt_bias,
                    float* __restrict__ xo, float* __restrict__ Bo,
                    float* __restrict__ Co, float* __restrict__ dto) {
  const int row = blockIdx.x;
  const int t   = row % SEQLEN;
  const int c   = threadIdx.x;

  if (c < CONV_DIM) {
    const float w0 = conv_w[c * 4 + 0], w1 = conv_w[c * 4 + 1];
    const float w2 = conv_w[c * 4 + 2], w3 = conv_w[c * 4 + 3];
    const float* base = zxbdt + (size_t)row * D_IN_PROJ + D_INNER + c;
    const float x0 = (t >= 3) ? base[-3 * D_IN_PROJ] : 0.0f;
    const float x1 = (t >= 2) ? base[-2 * D_IN_PROJ] : 0.0f;
    const float x2 = (t >= 1) ? base[-1 * D_IN_PROJ] : 0.0f;
    const float x3 = base[0];
    float acc = conv_b[c] + w0 * x0 + w1 * x1 + w2 * x2 + w3 * x3;
    float y = silu_f(acc);
    if (c < D_INNER) xo[(size_t)row * D_INNER + c] = y;
    else             Bo[(size_t)row * D_STATE + (c - D_INNER)] = y;
  } else if (c < CONV_DIM + D_STATE) {
    const int cc = c - CONV_DIM;
    const float w0 = conv_w_b[cc * 4 + 0], w1 = conv_w_b[cc * 4 + 1];
    const float w2 = conv_w_b[cc * 4 + 2], w3 = conv_w_b[cc * 4 + 3];
    const float* base = cproj + (size_t)row * D_STATE + cc;
    const float x0 = (t >= 3) ? base[-3 * D_STATE] : 0.0f;
    const float x1 = (t >= 2) ? base[-2 * D_STATE] : 0.0f;
    const float x2 = (t >= 1) ? base[-1 * D_STATE] : 0.0f;
    const float x3 = base[0];
    float acc = conv_b_b[cc] + w0 * x0 + w1 * x1 + w2 * x2 + w3 * x3;
    Co[(size_t)row * D_STATE + cc] = silu_f(acc);
  } else if (c < CONV_DIM + D_STATE + NHEADS) {
    const int h = c - CONV_DIM - D_STATE;
    float v = zxbdt[(size_t)row * D_IN_PROJ + (D_IN_PROJ - NHEADS) + h] + dt_bias[h];
    dto[(size_t)row * NHEADS + h] = softplus_f(v);
  }
}

// ---------------------------------------------------------------------------
// K3: per (head, chunk, batch) block. 256 threads = 256 chunk positions.
//  - inclusive scan of a = dt*A over the chunk (LDS Hillis-Steele)
//  - Y_diag[l,:] = sum_{s<=l} (C[l]·B[s]) exp(ac[l]-ac[s]) * xdt[s,:]
//  - local chunk state[p,n] = sum_l B[l,n] * exp(csum-ac[l]) * xdt[l,p]
// ---------------------------------------------------------------------------
__global__ __launch_bounds__(CHUNK)
void ssd_diag_kernel(const float* __restrict__ xo, const float* __restrict__ Bo,
                     const float* __restrict__ Co, const float* __restrict__ dto,
                     const float* __restrict__ A_log,
                     float* __restrict__ Ydiag, float* __restrict__ acum_g,
                     float* __restrict__ csum_g, float* __restrict__ stloc) {
  const int h    = blockIdx.x;
  const int cidx = blockIdx.y;
  const int b    = blockIdx.z;
  const int l    = threadIdx.x;
  const int t    = cidx * CHUNK + l;
  const size_t row = (size_t)b * SEQLEN + t;

  __shared__ float sc[CHUNK];            // a, then inclusive cumsum
  __shared__ float Bs[CHUNK][D_STATE];
  __shared__ float xs[CHUNK][HEADDIM];   // x * dt
  __shared__ float wdec[CHUNK];

  const float Ah  = -expf(A_log[h]);
  const float dtv = dto[row * NHEADS + h];
  sc[l] = dtv * Ah;
  __syncthreads();
#pragma unroll
  for (int off = 1; off < CHUNK; off <<= 1) {
    float v = (l >= off) ? sc[l - off] : 0.0f;
    __syncthreads();
    if (l >= off) sc[l] += v;
    __syncthreads();
  }
  const float acl  = sc[l];
  const float csum = sc[CHUNK - 1];
  acum_g[(size_t)(b * NHEADS + h) * SEQLEN + t] = acl;
  if (l == CHUNK - 1) csum_g[(b * NHEADS + h) * NCHUNKS + cidx] = acl;
  wdec[l] = __expf(csum - acl);

  // cooperative load of B chunk; per-thread load of own xdt row
  {
    const float4* bsrc = reinterpret_cast<const float4*>(Bo + ((size_t)b * SEQLEN + (size_t)cidx * CHUNK) * D_STATE);
    float4* bdst = reinterpret_cast<float4*>(&Bs[0][0]);
    for (int i = threadIdx.x; i < CHUNK * 4; i += CHUNK) bdst[i] = bsrc[i];
    const float4* xsrc = reinterpret_cast<const float4*>(xo + row * D_INNER + h * HEADDIM);
    float4* xdst = reinterpret_cast<float4*>(&xs[l][0]);
#pragma unroll
    for (int q = 0; q < 4; ++q) {
      float4 v = xsrc[q];
      v.x *= dtv; v.y *= dtv; v.z *= dtv; v.w *= dtv;
      xdst[q] = v;
    }
  }
  float cl[16];
  {
    const float4* csrc = reinterpret_cast<const float4*>(Co + row * D_STATE);
#pragma unroll
    for (int q = 0; q < 4; ++q) {
      float4 v = csrc[q];
      cl[q * 4 + 0] = v.x; cl[q * 4 + 1] = v.y; cl[q * 4 + 2] = v.z; cl[q * 4 + 3] = v.w;
    }
  }
  __syncthreads();

  // Y_diag: triangular accumulation
  float4 a0 = {0, 0, 0, 0}, a1 = {0, 0, 0, 0}, a2 = {0, 0, 0, 0}, a3 = {0, 0, 0, 0};
  for (int s = 0; s <= l; ++s) {
    const float4* br = reinterpret_cast<const float4*>(&Bs[s][0]);
    const float4 b0 = br[0], b1 = br[1], b2 = br[2], b3 = br[3];
    float g = cl[0] * b0.x + cl[1] * b0.y + cl[2] * b0.z + cl[3] * b0.w
            + cl[4] * b1.x + cl[5] * b1.y + cl[6] * b1.z + cl[7] * b1.w
            + cl[8] * b2.x + cl[9] * b2.y + cl[10] * b2.z + cl[11] * b2.w
            + cl[12] * b3.x + cl[13] * b3.y + cl[14] * b3.z + cl[15] * b3.w;
    const float w = __expf(acl - sc[s]) * g;
    const float4* xr = reinterpret_cast<const float4*>(&xs[s][0]);
    const float4 v0 = xr[0], v1 = xr[1], v2 = xr[2], v3 = xr[3];
    a0.x += w * v0.x; a0.y += w * v0.y; a0.z += w * v0.z; a0.w += w * v0.w;
    a1.x += w * v1.x; a1.y += w * v1.y; a1.z += w * v1.z; a1.w += w * v1.w;
    a2.x += w * v2.x; a2.y += w * v2.y; a2.z += w * v2.z; a2.w += w * v2.w;
    a3.x += w * v3.x; a3.y += w * v3.y; a3.z += w * v3.z; a3.w += w * v3.w;
  }
  float4* yout = reinterpret_cast<float4*>(Ydiag + row * D_INNER + h * HEADDIM);
  yout[0] = a0; yout[1] = a1; yout[2] = a2; yout[3] = a3;

  // local chunk state (no barrier needed: all LDS written before last barrier)
  const int p = threadIdx.x >> 4, n = threadIdx.x & 15;
  float st = 0.0f;
  for (int s = 0; s < CHUNK; ++s)
    st += Bs[s][n] * xs[s][p] * wdec[s];
  stloc[((size_t)(b * NCHUNKS + cidx) * NHEADS + h) * 256 + threadIdx.x] = st;
}

// ---------------------------------------------------------------------------
// K4: sequential inter-chunk state recurrence. 48 blocks (b,h) x 256 threads (p,n).
// stpre[c] = state ENTERING chunk c.
// ---------------------------------------------------------------------------
__global__ __launch_bounds__(256)
void chunk_scan_kernel(const float* __restrict__ stloc, const float* __restrict__ csum_g,
                       float* __restrict__ stpre) {
  const int b  = blockIdx.x / NHEADS;
  const int h  = blockIdx.x % NHEADS;
  const int pn = threadIdx.x;
  float S = 0.0f;
  for (int c = 0; c < NCHUNKS; ++c) {
    const size_t idx = ((size_t)(b * NCHUNKS + c) * NHEADS + h) * 256 + pn;
    stpre[idx] = S;
    S = __expf(csum_g[(b * NHEADS + h) * NCHUNKS + c]) * S + stloc[idx];
  }
}

// ---------------------------------------------------------------------------
// K5: Y_off + D*x, silu(z) gate, RMSNorm. One block per (b,t), 384 threads.
// Writes yn in-place over Ydiag.
// ---------------------------------------------------------------------------
__global__ __launch_bounds__(384)
void yoff_norm_kernel(float* __restrict__ Yd, const float* __restrict__ xo,
                      const float* __restrict__ Co, const float* __restrict__ acum_g,
                      const float* __restrict__ stpre, const float* __restrict__ Dvec,
                      const float* __restrict__ zxbdt, const float* __restrict__ norm_w) {
  const int row  = blockIdx.x;
  const int b    = row / SEQLEN, t = row % SEQLEN;
  const int cidx = t / CHUNK;
  const int d    = threadIdx.x;
  const int h    = d >> 4, p = d & 15;

  __shared__ float Cl[16];
  __shared__ float red[6];
  if (d < 16) Cl[d] = Co[(size_t)row * D_STATE + d];
  __syncthreads();

  const float* S = stpre + ((size_t)(b * NCHUNKS + cidx) * NHEADS + h) * 256 + p * 16;
  float dot = 0.0f;
#pragma unroll
  for (int n = 0; n < 16; ++n) dot += Cl[n] * S[n];
  const float acl = acum_g[(size_t)(b * NHEADS + h) * SEQLEN + t];
  float y = Yd[(size_t)row * D_INNER + d] + __expf(acl) * dot
          + Dvec[h] * xo[(size_t)row * D_INNER + d];
  const float z = zxbdt[(size_t)row * D_IN_PROJ + d];
  const float yg = y * silu_f(z);

  float v = yg * yg;
#pragma unroll
  for (int off = 32; off > 0; off >>= 1) v += __shfl_down(v, off);
  if ((d & 63) == 0) red[d >> 6] = v;
  __syncthreads();
  const float tot = red[0] + red[1] + red[2] + red[3] + red[4] + red[5];
  const float scale = rsqrtf(tot * (1.0f / D_INNER) + EPS);
  Yd[(size_t)row * D_INNER + d] = yg * scale * norm_w[d];
}

// ---------------------------------------------------------------------------
extern "C" void kernel_launch(void* const* d_in, const int* in_sizes, int n_in,
                              void* d_out, int out_size, void* d_ws, size_t ws_size,
                              hipStream_t stream) {
  const float* u        = (const float*)d_in[0];
  const float* support  = (const float*)d_in[1];
  const float* W_in     = (const float*)d_in[2];
  const float* W_in_b   = (const float*)d_in[3];
  const float* conv_w   = (const float*)d_in[4];
  const float* conv_b   = (const float*)d_in[5];
  const float* conv_w_b = (const float*)d_in[6];
  const float* conv_b_b = (const float*)d_in[7];
  const float* dt_bias  = (const float*)d_in[8];
  const float* A_log    = (const float*)d_in[9];
  const float* Dvec     = (const float*)d_in[10];
  const float* norm_w   = (const float*)d_in[11];
  const float* W_out    = (const float*)d_in[12];
  float* out = (float*)d_out;
  float* ws  = (float*)d_ws;

  // workspace layout (floats)
  float* zxbdt = ws;                                         // 16384*808
  float* cproj = zxbdt + (size_t)ROWS * D_IN_PROJ;           // 16384*16
  float* xo    = cproj + (size_t)ROWS * D_STATE;             // 16384*384
  float* Bo    = xo    + (size_t)ROWS * D_INNER;             // 16384*16
  float* Co    = Bo    + (size_t)ROWS * D_STATE;             // 16384*16
  float* dto   = Co    + (size_t)ROWS * D_STATE;             // 16384*24
  float* acum  = dto   + (size_t)ROWS * NHEADS;              // 2*24*8192
  float* csum  = acum  + (size_t)BATCH * NHEADS * SEQLEN;    // 2*24*32
  float* stloc = csum  + (size_t)BATCH * NHEADS * NCHUNKS;   // 2*32*24*256
  float* stpre = stloc + (size_t)BATCH * NCHUNKS * NHEADS * 256;
  float* Yd    = stpre + (size_t)BATCH * NCHUNKS * NHEADS * 256; // 16384*384 (reused as yn)

  // K1a: zxbdt = u @ W_in^T   (16384 x 808, K=192)
  gemm_nt<128, 64, 16, 8, 4><<<dim3((D_IN_PROJ + 63) / 64, ROWS / 128), 256, 0, stream>>>(
      u, W_in, zxbdt, ROWS, D_IN_PROJ, D_MODEL);
  // K1b: cproj = support @ W_in_b^T   (16384 x 16, K=192)
  gemm_nt<64, 16, 16, 4, 1><<<dim3(1, ROWS / 64), 256, 0, stream>>>(
      support, W_in_b, cproj, ROWS, D_STATE, D_MODEL);
  // K2: conv + silu + dt
  conv_dt_kernel<<<ROWS, 448, 0, stream>>>(zxbdt, cproj, conv_w, conv_b, conv_w_b,
                                           conv_b_b, dt_bias, xo, Bo, Co, dto);
  // K3: per-chunk diag + local states
  ssd_diag_kernel<<<dim3(NHEADS, NCHUNKS, BATCH), CHUNK, 0, stream>>>(
      xo, Bo, Co, dto, A_log, Yd, acum, csum, stloc);
  // K4: inter-chunk scan
  chunk_scan_kernel<<<BATCH * NHEADS, 256, 0, stream>>>(stloc, csum, stpre);
  // K5: Y_off + gate + RMSNorm (in-place into Yd)
  yoff_norm_kernel<<<ROWS, 384, 0, stream>>>(Yd, xo, Co, acum, stpre, Dvec, zxbdt, norm_w);
  // K6: out = yn @ W_out^T   (16384 x 192, K=384)
  gemm_nt<128, 64, 16, 8, 4><<<dim3(D_MODEL / 64, ROWS / 128), 256, 0, stream>>>(
      Yd, W_out, out, ROWS, D_MODEL, D_INNER);
}

// Round 2
// 259.485 us; speedup vs baseline: 1.4960x; 1.4960x over previous
//
#include <hip/hip_runtime.h>
#include <cmath>

#define ROWS      16384
#define SEQLEN    8192
#define BATCH     2
#define NHEADS    24
#define HEADDIM   16
#define D_STATE   16
#define D_INNER   384
#define D_MODEL   192
#define D_IN_PROJ 808
#define CONV_DIM  400
#define NCHUNKS   32
#define CHUNK     256
#define EPS       1e-5f

typedef short bf16x8 __attribute__((ext_vector_type(8)));
typedef float f32x4  __attribute__((ext_vector_type(4)));
typedef unsigned short us4 __attribute__((ext_vector_type(4)));

__device__ __forceinline__ float silu_f(float x) { return x / (1.0f + expf(-x)); }
__device__ __forceinline__ float softplus_f(float x) { return (x > 20.0f) ? x : log1pf(expf(x)); }
__device__ __forceinline__ unsigned short f2bf(float x) {
  unsigned u = __builtin_bit_cast(unsigned, x);
  u += 0x7fff + ((u >> 16) & 1);
  return (unsigned short)(u >> 16);
}

// ---------------------------------------------------------------------------
// MFMA bf16 GEMM: C[M,N] = A[M,K] * W[N,K]^T.  A fp32 or bf16 (A_BF16),
// W fp32 (converted during staging). BM=128 BN=64 BK=32, 4 waves (2x2).
// M % 128 == 0, K % 32 == 0; N guarded.
// ---------------------------------------------------------------------------
template<bool A_BF16>
__launch_bounds__(256, 2)
__global__ void gemm_mfma(const void* __restrict__ Ap, const float* __restrict__ W,
                          float* __restrict__ C, int M, int N, int K) {
  constexpr int BM = 128, BN = 64, BK = 32, LDK = BK + 8;  // 40 bf16 = 80B rows
  __shared__ unsigned short As[BM * LDK];
  __shared__ unsigned short Ws[BN * LDK];
  const int tid  = threadIdx.x;
  const int wid  = tid >> 6, lane = tid & 63;
  const int wr   = wid >> 1, wc = wid & 1;
  const int fr   = lane & 15, fq = lane >> 4;
  const long m0  = (long)blockIdx.y * BM;
  const int  n0  = blockIdx.x * BN;

  f32x4 acc[4][2] = {};

  for (int k0 = 0; k0 < K; k0 += BK) {
    // ---- stage A tile (128 x 32) ----
    if (A_BF16) {
      const unsigned short* A = (const unsigned short*)Ap;
#pragma unroll
      for (int p = 0; p < 4; ++p) {
        int flat = p * 1024 + tid * 4;
        int r = flat >> 5, c = flat & 31;
        us4 v = *(const us4*)(A + (m0 + r) * (long)K + k0 + c);
        *(us4*)&As[r * LDK + c] = v;
      }
    } else {
      const float* A = (const float*)Ap;
#pragma unroll
      for (int p = 0; p < 4; ++p) {
        int flat = p * 1024 + tid * 4;
        int r = flat >> 5, c = flat & 31;
        float4 v = *(const float4*)(A + (m0 + r) * (long)K + k0 + c);
        us4 o = { f2bf(v.x), f2bf(v.y), f2bf(v.z), f2bf(v.w) };
        *(us4*)&As[r * LDK + c] = o;
      }
    }
    // ---- stage W tile (64 x 32), guard N ----
#pragma unroll
    for (int p = 0; p < 2; ++p) {
      int flat = p * 1024 + tid * 4;
      int r = flat >> 5, c = flat & 31;
      int gn = n0 + r;
      float4 v;
      if (gn < N) v = *(const float4*)(W + (long)gn * K + k0 + c);
      else        v = make_float4(0.f, 0.f, 0.f, 0.f);
      us4 o = { f2bf(v.x), f2bf(v.y), f2bf(v.z), f2bf(v.w) };
      *(us4*)&Ws[r * LDK + c] = o;
    }
    __syncthreads();

    bf16x8 af[4], bf[2];
#pragma unroll
    for (int m = 0; m < 4; ++m) {
      int row = wr * 64 + m * 16 + fr;
      af[m] = *(const bf16x8*)&As[row * LDK + fq * 8];
    }
#pragma unroll
    for (int n = 0; n < 2; ++n) {
      int col = wc * 32 + n * 16 + fr;
      bf[n] = *(const bf16x8*)&Ws[col * LDK + fq * 8];
    }
#pragma unroll
    for (int m = 0; m < 4; ++m)
#pragma unroll
      for (int n = 0; n < 2; ++n)
        acc[m][n] = __builtin_amdgcn_mfma_f32_16x16x32_bf16(af[m], bf[n], acc[m][n], 0, 0, 0);
    __syncthreads();
  }

#pragma unroll
  for (int m = 0; m < 4; ++m)
#pragma unroll
    for (int n = 0; n < 2; ++n)
#pragma unroll
      for (int j = 0; j < 4; ++j) {
        long gm = m0 + wr * 64 + m * 16 + fq * 4 + j;
        int  gn = n0 + wc * 32 + n * 16 + fr;
        if (gn < N) C[gm * N + gn] = acc[m][n][j];
      }
}

// ---------------------------------------------------------------------------
// fp32 SIMT GEMM (kept for the tiny K1b: N=16)
// ---------------------------------------------------------------------------
template<int BM, int BN, int BK, int TM, int TN>
__launch_bounds__((BM / TM) * (BN / TN))
__global__ void gemm_nt(const float* __restrict__ A, const float* __restrict__ W,
                        float* __restrict__ C, int M, int N, int K) {
  __shared__ float As[BK][BM + 4];
  __shared__ float Ws[BK][BN + 4];
  constexpr int NTX = BN / TN;
  constexpr int NT  = (BM / TM) * (BN / TN);
  const int tid = threadIdx.x;
  const int tx  = tid % NTX;
  const int ty  = tid / NTX;
  const long m0 = (long)blockIdx.y * BM;
  const long n0 = (long)blockIdx.x * BN;
  float acc[TM][TN] = {};

  for (int k0 = 0; k0 < K; k0 += BK) {
    for (int i = tid; i < BM * BK; i += NT) {
      int m = i / BK, kk = i % BK;
      long gm = m0 + m;
      As[kk][m] = (gm < M) ? A[gm * K + (k0 + kk)] : 0.0f;
    }
    for (int i = tid; i < BN * BK; i += NT) {
      int n = i / BK, kk = i % BK;
      long gn = n0 + n;
      Ws[kk][n] = (gn < N) ? W[gn * K + (k0 + kk)] : 0.0f;
    }
    __syncthreads();
#pragma unroll
    for (int kk = 0; kk < BK; ++kk) {
      float a[TM], w[TN];
#pragma unroll
      for (int i = 0; i < TM; ++i) a[i] = As[kk][ty * TM + i];
#pragma unroll
      for (int j = 0; j < TN; ++j) w[j] = Ws[kk][tx * TN + j];
#pragma unroll
      for (int i = 0; i < TM; ++i)
#pragma unroll
        for (int j = 0; j < TN; ++j)
          acc[i][j] += a[i] * w[j];
    }
    __syncthreads();
  }
#pragma unroll
  for (int i = 0; i < TM; ++i) {
    long gm = m0 + ty * TM + i;
    if (gm >= M) continue;
#pragma unroll
    for (int j = 0; j < TN; ++j) {
      long gn = n0 + tx * TN + j;
      if (gn < N) C[gm * N + gn] = acc[i][j];
    }
  }
}

// ---------------------------------------------------------------------------
// K2: depthwise causal conv (width 4) + silu + dt softplus
// ---------------------------------------------------------------------------
__global__ __launch_bounds__(448)
void conv_dt_kernel(const float* __restrict__ zxbdt, const float* __restrict__ cproj,
                    const float* __restrict__ conv_w, const float* __restrict__ conv_b,
                    const float* __restrict__ conv_w_b, const float* __restrict__ conv_b_b,
                    const float* __restrict__ dt_bias,
                    float* __restrict__ xo, float* __restrict__ Bo,
                    float* __restrict__ Co, float* __restrict__ dto) {
  const int row = blockIdx.x;
  const int t   = row % SEQLEN;
  const int c   = threadIdx.x;

  if (c < CONV_DIM) {
    const float w0 = conv_w[c * 4 + 0], w1 = conv_w[c * 4 + 1];
    const float w2 = conv_w[c * 4 + 2], w3 = conv_w[c * 4 + 3];
    const float* base = zxbdt + (size_t)row * D_IN_PROJ + D_INNER + c;
    const float x0 = (t >= 3) ? base[-3 * D_IN_PROJ] : 0.0f;
    const float x1 = (t >= 2) ? base[-2 * D_IN_PROJ] : 0.0f;
    const float x2 = (t >= 1) ? base[-1 * D_IN_PROJ] : 0.0f;
    const float x3 = base[0];
    float acc = conv_b[c] + w0 * x0 + w1 * x1 + w2 * x2 + w3 * x3;
    float y = silu_f(acc);
    if (c < D_INNER) xo[(size_t)row * D_INNER + c] = y;
    else             Bo[(size_t)row * D_STATE + (c - D_INNER)] = y;
  } else if (c < CONV_DIM + D_STATE) {
    const int cc = c - CONV_DIM;
    const float w0 = conv_w_b[cc * 4 + 0], w1 = conv_w_b[cc * 4 + 1];
    const float w2 = conv_w_b[cc * 4 + 2], w3 = conv_w_b[cc * 4 + 3];
    const float* base = cproj + (size_t)row * D_STATE + cc;
    const float x0 = (t >= 3) ? base[-3 * D_STATE] : 0.0f;
    const float x1 = (t >= 2) ? base[-2 * D_STATE] : 0.0f;
    const float x2 = (t >= 1) ? base[-1 * D_STATE] : 0.0f;
    const float x3 = base[0];
    float acc = conv_b_b[cc] + w0 * x0 + w1 * x1 + w2 * x2 + w3 * x3;
    Co[(size_t)row * D_STATE + cc] = silu_f(acc);
  } else if (c < CONV_DIM + D_STATE + NHEADS) {
    const int h = c - CONV_DIM - D_STATE;
    float v = zxbdt[(size_t)row * D_IN_PROJ + (D_IN_PROJ - NHEADS) + h] + dt_bias[h];
    dto[(size_t)row * NHEADS + h] = softplus_f(v);
  }
}

// ---------------------------------------------------------------------------
// K3: per (head, chunk, batch): cumsum scan, Y_diag, local chunk state
// ---------------------------------------------------------------------------
__global__ __launch_bounds__(CHUNK)
void ssd_diag_kernel(const float* __restrict__ xo, const float* __restrict__ Bo,
                     const float* __restrict__ Co, const float* __restrict__ dto,
                     const float* __restrict__ A_log,
                     float* __restrict__ Ydiag, float* __restrict__ acum_g,
                     float* __restrict__ csum_g, float* __restrict__ stloc) {
  const int h    = blockIdx.x;
  const int cidx = blockIdx.y;
  const int b    = blockIdx.z;
  const int l    = threadIdx.x;
  const int t    = cidx * CHUNK + l;
  const size_t row = (size_t)b * SEQLEN + t;

  __shared__ float sc[CHUNK];
  __shared__ float Bs[CHUNK][D_STATE];
  __shared__ float xs[CHUNK][HEADDIM];
  __shared__ float wdec[CHUNK];

  const float Ah  = -expf(A_log[h]);
  const float dtv = dto[row * NHEADS + h];
  sc[l] = dtv * Ah;
  __syncthreads();
#pragma unroll
  for (int off = 1; off < CHUNK; off <<= 1) {
    float v = (l >= off) ? sc[l - off] : 0.0f;
    __syncthreads();
    if (l >= off) sc[l] += v;
    __syncthreads();
  }
  const float acl  = sc[l];
  const float csum = sc[CHUNK - 1];
  acum_g[(size_t)(b * NHEADS + h) * SEQLEN + t] = acl;
  if (l == CHUNK - 1) csum_g[(b * NHEADS + h) * NCHUNKS + cidx] = acl;
  wdec[l] = __expf(csum - acl);

  {
    const float4* bsrc = reinterpret_cast<const float4*>(Bo + ((size_t)b * SEQLEN + (size_t)cidx * CHUNK) * D_STATE);
    float4* bdst = reinterpret_cast<float4*>(&Bs[0][0]);
    for (int i = threadIdx.x; i < CHUNK * 4; i += CHUNK) bdst[i] = bsrc[i];
    const float4* xsrc = reinterpret_cast<const float4*>(xo + row * D_INNER + h * HEADDIM);
    float4* xdst = reinterpret_cast<float4*>(&xs[l][0]);
#pragma unroll
    for (int q = 0; q < 4; ++q) {
      float4 v = xsrc[q];
      v.x *= dtv; v.y *= dtv; v.z *= dtv; v.w *= dtv;
      xdst[q] = v;
    }
  }
  float cl[16];
  {
    const float4* csrc = reinterpret_cast<const float4*>(Co + row * D_STATE);
#pragma unroll
    for (int q = 0; q < 4; ++q) {
      float4 v = csrc[q];
      cl[q * 4 + 0] = v.x; cl[q * 4 + 1] = v.y; cl[q * 4 + 2] = v.z; cl[q * 4 + 3] = v.w;
    }
  }
  __syncthreads();

  float4 a0 = {0, 0, 0, 0}, a1 = {0, 0, 0, 0}, a2 = {0, 0, 0, 0}, a3 = {0, 0, 0, 0};
  for (int s = 0; s <= l; ++s) {
    const float4* br = reinterpret_cast<const float4*>(&Bs[s][0]);
    const float4 b0 = br[0], b1 = br[1], b2 = br[2], b3 = br[3];
    float g = cl[0] * b0.x + cl[1] * b0.y + cl[2] * b0.z + cl[3] * b0.w
            + cl[4] * b1.x + cl[5] * b1.y + cl[6] * b1.z + cl[7] * b1.w
            + cl[8] * b2.x + cl[9] * b2.y + cl[10] * b2.z + cl[11] * b2.w
            + cl[12] * b3.x + cl[13] * b3.y + cl[14] * b3.z + cl[15] * b3.w;
    const float w = __expf(acl - sc[s]) * g;
    const float4* xr = reinterpret_cast<const float4*>(&xs[s][0]);
    const float4 v0 = xr[0], v1 = xr[1], v2 = xr[2], v3 = xr[3];
    a0.x += w * v0.x; a0.y += w * v0.y; a0.z += w * v0.z; a0.w += w * v0.w;
    a1.x += w * v1.x; a1.y += w * v1.y; a1.z += w * v1.z; a1.w += w * v1.w;
    a2.x += w * v2.x; a2.y += w * v2.y; a2.z += w * v2.z; a2.w += w * v2.w;
    a3.x += w * v3.x; a3.y += w * v3.y; a3.z += w * v3.z; a3.w += w * v3.w;
  }
  float4* yout = reinterpret_cast<float4*>(Ydiag + row * D_INNER + h * HEADDIM);
  yout[0] = a0; yout[1] = a1; yout[2] = a2; yout[3] = a3;

  const int p = threadIdx.x >> 4, n = threadIdx.x & 15;
  float st = 0.0f;
  for (int s = 0; s < CHUNK; ++s)
    st += Bs[s][n] * xs[s][p] * wdec[s];
  stloc[((size_t)(b * NCHUNKS + cidx) * NHEADS + h) * 256 + threadIdx.x] = st;
}

// ---------------------------------------------------------------------------
// K4: sequential inter-chunk state recurrence
// ---------------------------------------------------------------------------
__global__ __launch_bounds__(256)
void chunk_scan_kernel(const float* __restrict__ stloc, const float* __restrict__ csum_g,
                       float* __restrict__ stpre) {
  const int b  = blockIdx.x / NHEADS;
  const int h  = blockIdx.x % NHEADS;
  const int pn = threadIdx.x;
  float S = 0.0f;
  for (int c = 0; c < NCHUNKS; ++c) {
    const size_t idx = ((size_t)(b * NCHUNKS + c) * NHEADS + h) * 256 + pn;
    stpre[idx] = S;
    S = __expf(csum_g[(b * NHEADS + h) * NCHUNKS + c]) * S + stloc[idx];
  }
}

// ---------------------------------------------------------------------------
// K5: Y_off + D*x, silu(z) gate, RMSNorm (in-place into Yd, fp32)
// ---------------------------------------------------------------------------
__global__ __launch_bounds__(384)
void yoff_norm_kernel(float* __restrict__ Yd, const float* __restrict__ xo,
                      const float* __restrict__ Co, const float* __restrict__ acum_g,
                      const float* __restrict__ stpre, const float* __restrict__ Dvec,
                      const float* __restrict__ zxbdt, const float* __restrict__ norm_w) {
  const int row  = blockIdx.x;
  const int b    = row / SEQLEN, t = row % SEQLEN;
  const int cidx = t / CHUNK;
  const int d    = threadIdx.x;
  const int h    = d >> 4, p = d & 15;

  __shared__ float Cl[16];
  __shared__ float red[6];
  if (d < 16) Cl[d] = Co[(size_t)row * D_STATE + d];
  __syncthreads();

  const float* S = stpre + ((size_t)(b * NCHUNKS + cidx) * NHEADS + h) * 256 + p * 16;
  float dot = 0.0f;
#pragma unroll
  for (int n = 0; n < 16; ++n) dot += Cl[n] * S[n];
  const float acl = acum_g[(size_t)(b * NHEADS + h) * SEQLEN + t];
  float y = Yd[(size_t)row * D_INNER + d] + __expf(acl) * dot
          + Dvec[h] * xo[(size_t)row * D_INNER + d];
  const float z = zxbdt[(size_t)row * D_IN_PROJ + d];
  const float yg = y * silu_f(z);

  float v = yg * yg;
#pragma unroll
  for (int off = 32; off > 0; off >>= 1) v += __shfl_down(v, off);
  if ((d & 63) == 0) red[d >> 6] = v;
  __syncthreads();
  const float tot = red[0] + red[1] + red[2] + red[3] + red[4] + red[5];
  const float scale = rsqrtf(tot * (1.0f / D_INNER) + EPS);
  Yd[(size_t)row * D_INNER + d] = yg * scale * norm_w[d];
}

// ---------------------------------------------------------------------------
extern "C" void kernel_launch(void* const* d_in, const int* in_sizes, int n_in,
                              void* d_out, int out_size, void* d_ws, size_t ws_size,
                              hipStream_t stream) {
  const float* u        = (const float*)d_in[0];
  const float* support  = (const float*)d_in[1];
  const float* W_in     = (const float*)d_in[2];
  const float* W_in_b   = (const float*)d_in[3];
  const float* conv_w   = (const float*)d_in[4];
  const float* conv_b   = (const float*)d_in[5];
  const float* conv_w_b = (const float*)d_in[6];
  const float* conv_b_b = (const float*)d_in[7];
  const float* dt_bias  = (const float*)d_in[8];
  const float* A_log    = (const float*)d_in[9];
  const float* Dvec     = (const float*)d_in[10];
  const float* norm_w   = (const float*)d_in[11];
  const float* W_out    = (const float*)d_in[12];
  float* out = (float*)d_out;
  float* ws  = (float*)d_ws;

  float* zxbdt = ws;                                         // 16384*808
  float* cproj = zxbdt + (size_t)ROWS * D_IN_PROJ;           // 16384*16
  float* xo    = cproj + (size_t)ROWS * D_STATE;             // 16384*384
  float* Bo    = xo    + (size_t)ROWS * D_INNER;             // 16384*16
  float* Co    = Bo    + (size_t)ROWS * D_STATE;             // 16384*16
  float* dto   = Co    + (size_t)ROWS * D_STATE;             // 16384*24
  float* acum  = dto   + (size_t)ROWS * NHEADS;              // 2*24*8192
  float* csum  = acum  + (size_t)BATCH * NHEADS * SEQLEN;    // 2*24*32
  float* stloc = csum  + (size_t)BATCH * NHEADS * NCHUNKS;   // 2*32*24*256
  float* stpre = stloc + (size_t)BATCH * NCHUNKS * NHEADS * 256;
  float* Yd    = stpre + (size_t)BATCH * NCHUNKS * NHEADS * 256; // 16384*384

  // K1a: zxbdt = u @ W_in^T   (MFMA bf16)
  gemm_mfma<false><<<dim3((D_IN_PROJ + 63) / 64, ROWS / 128), 256, 0, stream>>>(
      u, W_in, zxbdt, ROWS, D_IN_PROJ, D_MODEL);
  // K1b: cproj = support @ W_in_b^T (tiny, SIMT)
  gemm_nt<64, 16, 16, 4, 1><<<dim3(1, ROWS / 64), 256, 0, stream>>>(
      support, W_in_b, cproj, ROWS, D_STATE, D_MODEL);
  // K2: conv + silu + dt
  conv_dt_kernel<<<ROWS, 448, 0, stream>>>(zxbdt, cproj, conv_w, conv_b, conv_w_b,
                                           conv_b_b, dt_bias, xo, Bo, Co, dto);
  // K3
  ssd_diag_kernel<<<dim3(NHEADS, NCHUNKS, BATCH), CHUNK, 0, stream>>>(
      xo, Bo, Co, dto, A_log, Yd, acum, csum, stloc);
  // K4
  chunk_scan_kernel<<<BATCH * NHEADS, 256, 0, stream>>>(stloc, csum, stpre);
  // K5
  yoff_norm_kernel<<<ROWS, 384, 0, stream>>>(Yd, xo, Co, acum, stpre, Dvec, zxbdt, norm_w);
  // K6: out = yn @ W_out^T   (MFMA bf16, A converted from fp32 Yd)
  gemm_mfma<false><<<dim3(D_MODEL / 64, ROWS / 128), 256, 0, stream>>>(
      Yd, W_out, out, ROWS, D_MODEL, D_INNER);
}

// Round 3
// 199.077 us; speedup vs baseline: 1.9499x; 1.3034x over previous
//
#include <hip/hip_runtime.h>
#include <cmath>

#define ROWS      16384
#define SEQLEN    8192
#define BATCH     2
#define NHEADS    24
#define HEADDIM   16
#define D_STATE   16
#define D_INNER   384
#define D_MODEL   192
#define D_IN_PROJ 808
#define CONV_DIM  400
#define NCHUNKS   32
#define CHUNK     256
#define EPS       1e-5f

typedef short bf16x8 __attribute__((ext_vector_type(8)));
typedef float f32x4  __attribute__((ext_vector_type(4)));
typedef unsigned short us4 __attribute__((ext_vector_type(4)));

__device__ __forceinline__ float silu_f(float x) { return x / (1.0f + expf(-x)); }
__device__ __forceinline__ float softplus_f(float x) { return (x > 20.0f) ? x : log1pf(expf(x)); }
__device__ __forceinline__ unsigned short f2bf(float x) {
  unsigned u = __builtin_bit_cast(unsigned, x);
  u += 0x7fff + ((u >> 16) & 1);
  return (unsigned short)(u >> 16);
}

// ---------------------------------------------------------------------------
// MFMA bf16 GEMM: C[M,N] = A[M,K] * W[N,K]^T  (A fp32, converted in staging)
// ---------------------------------------------------------------------------
template<bool A_BF16>
__launch_bounds__(256, 2)
__global__ void gemm_mfma(const void* __restrict__ Ap, const float* __restrict__ W,
                          float* __restrict__ C, int M, int N, int K) {
  constexpr int BM = 128, BN = 64, BK = 32, LDK = BK + 8;
  __shared__ unsigned short As[BM * LDK];
  __shared__ unsigned short Ws[BN * LDK];
  const int tid  = threadIdx.x;
  const int wid  = tid >> 6, lane = tid & 63;
  const int wr   = wid >> 1, wc = wid & 1;
  const int fr   = lane & 15, fq = lane >> 4;
  const long m0  = (long)blockIdx.y * BM;
  const int  n0  = blockIdx.x * BN;

  f32x4 acc[4][2] = {};

  for (int k0 = 0; k0 < K; k0 += BK) {
    if (A_BF16) {
      const unsigned short* A = (const unsigned short*)Ap;
#pragma unroll
      for (int p = 0; p < 4; ++p) {
        int flat = p * 1024 + tid * 4;
        int r = flat >> 5, c = flat & 31;
        us4 v = *(const us4*)(A + (m0 + r) * (long)K + k0 + c);
        *(us4*)&As[r * LDK + c] = v;
      }
    } else {
      const float* A = (const float*)Ap;
#pragma unroll
      for (int p = 0; p < 4; ++p) {
        int flat = p * 1024 + tid * 4;
        int r = flat >> 5, c = flat & 31;
        float4 v = *(const float4*)(A + (m0 + r) * (long)K + k0 + c);
        us4 o = { f2bf(v.x), f2bf(v.y), f2bf(v.z), f2bf(v.w) };
        *(us4*)&As[r * LDK + c] = o;
      }
    }
#pragma unroll
    for (int p = 0; p < 2; ++p) {
      int flat = p * 1024 + tid * 4;
      int r = flat >> 5, c = flat & 31;
      int gn = n0 + r;
      float4 v;
      if (gn < N) v = *(const float4*)(W + (long)gn * K + k0 + c);
      else        v = make_float4(0.f, 0.f, 0.f, 0.f);
      us4 o = { f2bf(v.x), f2bf(v.y), f2bf(v.z), f2bf(v.w) };
      *(us4*)&Ws[r * LDK + c] = o;
    }
    __syncthreads();

    bf16x8 af[4], bf[2];
#pragma unroll
    for (int m = 0; m < 4; ++m) {
      int row = wr * 64 + m * 16 + fr;
      af[m] = *(const bf16x8*)&As[row * LDK + fq * 8];
    }
#pragma unroll
    for (int n = 0; n < 2; ++n) {
      int col = wc * 32 + n * 16 + fr;
      bf[n] = *(const bf16x8*)&Ws[col * LDK + fq * 8];
    }
#pragma unroll
    for (int m = 0; m < 4; ++m)
#pragma unroll
      for (int n = 0; n < 2; ++n)
        acc[m][n] = __builtin_amdgcn_mfma_f32_16x16x32_bf16(af[m], bf[n], acc[m][n], 0, 0, 0);
    __syncthreads();
  }

#pragma unroll
  for (int m = 0; m < 4; ++m)
#pragma unroll
    for (int n = 0; n < 2; ++n)
#pragma unroll
      for (int j = 0; j < 4; ++j) {
        long gm = m0 + wr * 64 + m * 16 + fq * 4 + j;
        int  gn = n0 + wc * 32 + n * 16 + fr;
        if (gn < N) C[gm * N + gn] = acc[m][n][j];
      }
}

// ---------------------------------------------------------------------------
// fp32 SIMT GEMM (tiny K1b only)
// ---------------------------------------------------------------------------
template<int BM, int BN, int BK, int TM, int TN>
__launch_bounds__((BM / TM) * (BN / TN))
__global__ void gemm_nt(const float* __restrict__ A, const float* __restrict__ W,
                        float* __restrict__ C, int M, int N, int K) {
  __shared__ float As[BK][BM + 4];
  __shared__ float Ws[BK][BN + 4];
  constexpr int NTX = BN / TN;
  constexpr int NT  = (BM / TM) * (BN / TN);
  const int tid = threadIdx.x;
  const int tx  = tid % NTX;
  const int ty  = tid / NTX;
  const long m0 = (long)blockIdx.y * BM;
  const long n0 = (long)blockIdx.x * BN;
  float acc[TM][TN] = {};

  for (int k0 = 0; k0 < K; k0 += BK) {
    for (int i = tid; i < BM * BK; i += NT) {
      int m = i / BK, kk = i % BK;
      long gm = m0 + m;
      As[kk][m] = (gm < M) ? A[gm * K + (k0 + kk)] : 0.0f;
    }
    for (int i = tid; i < BN * BK; i += NT) {
      int n = i / BK, kk = i % BK;
      long gn = n0 + n;
      Ws[kk][n] = (gn < N) ? W[gn * K + (k0 + kk)] : 0.0f;
    }
    __syncthreads();
#pragma unroll
    for (int kk = 0; kk < BK; ++kk) {
      float a[TM], w[TN];
#pragma unroll
      for (int i = 0; i < TM; ++i) a[i] = As[kk][ty * TM + i];
#pragma unroll
      for (int j = 0; j < TN; ++j) w[j] = Ws[kk][tx * TN + j];
#pragma unroll
      for (int i = 0; i < TM; ++i)
#pragma unroll
        for (int j = 0; j < TN; ++j)
          acc[i][j] += a[i] * w[j];
    }
    __syncthreads();
  }
#pragma unroll
  for (int i = 0; i < TM; ++i) {
    long gm = m0 + ty * TM + i;
    if (gm >= M) continue;
#pragma unroll
    for (int j = 0; j < TN; ++j) {
      long gn = n0 + tx * TN + j;
      if (gn < N) C[gm * N + gn] = acc[i][j];
    }
  }
}

// ---------------------------------------------------------------------------
// K2: depthwise causal conv (width 4) + silu + dt softplus
// ---------------------------------------------------------------------------
__global__ __launch_bounds__(448)
void conv_dt_kernel(const float* __restrict__ zxbdt, const float* __restrict__ cproj,
                    const float* __restrict__ conv_w, const float* __restrict__ conv_b,
                    const float* __restrict__ conv_w_b, const float* __restrict__ conv_b_b,
                    const float* __restrict__ dt_bias,
                    float* __restrict__ xo, float* __restrict__ Bo,
                    float* __restrict__ Co, float* __restrict__ dto) {
  const int row = blockIdx.x;
  const int t   = row % SEQLEN;
  const int c   = threadIdx.x;

  if (c < CONV_DIM) {
    const float w0 = conv_w[c * 4 + 0], w1 = conv_w[c * 4 + 1];
    const float w2 = conv_w[c * 4 + 2], w3 = conv_w[c * 4 + 3];
    const float* base = zxbdt + (size_t)row * D_IN_PROJ + D_INNER + c;
    const float x0 = (t >= 3) ? base[-3 * D_IN_PROJ] : 0.0f;
    const float x1 = (t >= 2) ? base[-2 * D_IN_PROJ] : 0.0f;
    const float x2 = (t >= 1) ? base[-1 * D_IN_PROJ] : 0.0f;
    const float x3 = base[0];
    float acc = conv_b[c] + w0 * x0 + w1 * x1 + w2 * x2 + w3 * x3;
    float y = silu_f(acc);
    if (c < D_INNER) xo[(size_t)row * D_INNER + c] = y;
    else             Bo[(size_t)row * D_STATE + (c - D_INNER)] = y;
  } else if (c < CONV_DIM + D_STATE) {
    const int cc = c - CONV_DIM;
    const float w0 = conv_w_b[cc * 4 + 0], w1 = conv_w_b[cc * 4 + 1];
    const float w2 = conv_w_b[cc * 4 + 2], w3 = conv_w_b[cc * 4 + 3];
    const float* base = cproj + (size_t)row * D_STATE + cc;
    const float x0 = (t >= 3) ? base[-3 * D_STATE] : 0.0f;
    const float x1 = (t >= 2) ? base[-2 * D_STATE] : 0.0f;
    const float x2 = (t >= 1) ? base[-1 * D_STATE] : 0.0f;
    const float x3 = base[0];
    float acc = conv_b_b[cc] + w0 * x0 + w1 * x1 + w2 * x2 + w3 * x3;
    Co[(size_t)row * D_STATE + cc] = silu_f(acc);
  } else if (c < CONV_DIM + D_STATE + NHEADS) {
    const int h = c - CONV_DIM - D_STATE;
    float v = zxbdt[(size_t)row * D_IN_PROJ + (D_IN_PROJ - NHEADS) + h] + dt_bias[h];
    dto[(size_t)row * NHEADS + h] = softplus_f(v);
  }
}

// ---------------------------------------------------------------------------
// K3 (MFMA): per (h, chunk, b) block, 4 waves.
//  G tile:  D[s][r] = B_tile(16x16,K=n zero-padded to 32) . C_strip^T
//           -> lane holds P[r=lane&15][s=4g+jr]  (C/D layout)
//  P relay: per-wave LDS scratch Ps[r][32]  (2 tiles packed -> K=32)
//  Y tile:  D[p][r] = xdtT(16x32) . P^T(32x16), accumulated over s-pairs
//  state:   D[n][p] = BwT(16x32) . xsT-as-B, K split across waves + reduce
// ---------------------------------------------------------------------------
__global__ __launch_bounds__(256, 2)
void ssd_mfma_kernel(const float* __restrict__ xo, const float* __restrict__ Bo,
                     const float* __restrict__ Co, const float* __restrict__ dto,
                     const float* __restrict__ A_log,
                     float* __restrict__ Ydiag, float* __restrict__ acum_g,
                     float* __restrict__ csum_g, float* __restrict__ stloc) {
  const int h    = blockIdx.x;
  const int cidx = blockIdx.y;
  const int b    = blockIdx.z;
  const int l    = threadIdx.x;
  const int t    = cidx * CHUNK + l;
  const size_t row = (size_t)b * SEQLEN + t;
  const int wid = l >> 6, lane = l & 63;
  const int fr  = lane & 15, g = lane >> 4;

  __shared__ unsigned short Bs[256 * 24 + 32]; // B rows, stride 24 (pad finite-zeroed)
  __shared__ unsigned short Cs[256 * 40];      // C rows, cols16..31 ZERO (K-pad)
  __shared__ unsigned short xsT[16 * 264];     // xdt transposed [p][l]
  __shared__ unsigned short BwT[16 * 264];     // (B*wdec)^T [n][l]
  __shared__ unsigned short Ps[4][16 * 40];    // per-wave P scratch [r][s0..31]
  __shared__ float sc[CHUNK];
  __shared__ float sred[4 * 256];

  const float Ah  = -expf(A_log[h]);
  const float dtv = dto[row * NHEADS + h];
  sc[l] = dtv * Ah;

  // ---- stage B, C, xdt (thread l owns chunk row l) ----
  float bv[16];
  {
    const us4 z4 = {0, 0, 0, 0};
    const float4* bp = (const float4*)(Bo + row * D_STATE);
#pragma unroll
    for (int q = 0; q < 4; ++q) {
      float4 v = bp[q];
      bv[4 * q + 0] = v.x; bv[4 * q + 1] = v.y; bv[4 * q + 2] = v.z; bv[4 * q + 3] = v.w;
      us4 o = { f2bf(v.x), f2bf(v.y), f2bf(v.z), f2bf(v.w) };
      *(us4*)&Bs[l * 24 + 4 * q] = o;
    }
    *(us4*)&Bs[l * 24 + 16] = z4;
    *(us4*)&Bs[l * 24 + 20] = z4;
    if (l < 32) Bs[256 * 24 + l] = 0;
    const float4* cp = (const float4*)(Co + row * D_STATE);
#pragma unroll
    for (int q = 0; q < 4; ++q) {
      float4 v = cp[q];
      us4 o = { f2bf(v.x), f2bf(v.y), f2bf(v.z), f2bf(v.w) };
      *(us4*)&Cs[l * 40 + 4 * q] = o;
      *(us4*)&Cs[l * 40 + 16 + 4 * q] = z4;
    }
    const float4* xp = (const float4*)(xo + row * D_INNER + h * HEADDIM);
#pragma unroll
    for (int q = 0; q < 4; ++q) {
      float4 v = xp[q];
      xsT[(4 * q + 0) * 264 + l] = f2bf(v.x * dtv);
      xsT[(4 * q + 1) * 264 + l] = f2bf(v.y * dtv);
      xsT[(4 * q + 2) * 264 + l] = f2bf(v.z * dtv);
      xsT[(4 * q + 3) * 264 + l] = f2bf(v.w * dtv);
    }
  }
  __syncthreads();

  // ---- inclusive cumsum of a over chunk ----
#pragma unroll
  for (int off = 1; off < CHUNK; off <<= 1) {
    float v = (l >= off) ? sc[l - off] : 0.0f;
    __syncthreads();
    if (l >= off) sc[l] += v;
    __syncthreads();
  }
  const float acl_self = sc[l];
  const float ctot     = sc[CHUNK - 1];
  acum_g[(size_t)(b * NHEADS + h) * SEQLEN + t] = acl_self;
  if (l == CHUNK - 1) csum_g[(b * NHEADS + h) * NCHUNKS + cidx] = acl_self;
  const float wdv = __expf(ctot - acl_self);
#pragma unroll
  for (int n = 0; n < 16; ++n)
    BwT[n * 264 + l] = f2bf(bv[n] * wdv);
  __syncthreads();

  // ---- chunk state: D[n][p], K=256 split across 4 waves ----
  {
    f32x4 accS = {};
    const int s0 = wid * 64;
#pragma unroll
    for (int k2 = 0; k2 < 2; ++k2) {
      bf16x8 af = *(const bf16x8*)&BwT[fr * 264 + s0 + 32 * k2 + 8 * g];
      bf16x8 bb = *(const bf16x8*)&xsT[fr * 264 + s0 + 32 * k2 + 8 * g];
      accS = __builtin_amdgcn_mfma_f32_16x16x32_bf16(af, bb, accS, 0, 0, 0);
    }
    // lane holds state[n=4g+jr][p=fr] -> store [p][n] layout
    *(f32x4*)&sred[wid * 256 + fr * 16 + 4 * g] = accS;
  }

  // ---- Y_diag: strips {wid,7-wid,8+wid,15-wid} (34 tiles/wave, balanced) ----
  const int strips[4] = { wid, 7 - wid, 8 + wid, 15 - wid };
  const f32x4 zf = {0.f, 0.f, 0.f, 0.f};
#pragma unroll
  for (int q = 0; q < 4; ++q) {
    const int lt = strips[q];
    f32x4 acc = zf;
    const bf16x8 cf = *(const bf16x8*)&Cs[(lt * 16 + fr) * 40 + 8 * g];
    const float acl = sc[lt * 16 + fr];
    const int   lg  = lt * 16 + fr;
    const int npair = (lt + 2) >> 1;
    for (int sp = 0; sp < npair; ++sp) {
#pragma unroll
      for (int ti = 0; ti < 2; ++ti) {
        const int st = 2 * sp + ti;
        if (st <= lt) {
          bf16x8 bfg = *(const bf16x8*)&Bs[(st * 16 + fr) * 24 + 8 * g];
          f32x4 G = __builtin_amdgcn_mfma_f32_16x16x32_bf16(bfg, cf, zf, 0, 0, 0);
          f32x4 se = *(const f32x4*)&sc[st * 16 + 4 * g];
          uint2 pk;
          {
            const int sbase = st * 16 + 4 * g;
            float w0 = (sbase + 0 <= lg) ? __expf(acl - se[0]) : 0.f;
            float w1 = (sbase + 1 <= lg) ? __expf(acl - se[1]) : 0.f;
            float w2 = (sbase + 2 <= lg) ? __expf(acl - se[2]) : 0.f;
            float w3 = (sbase + 3 <= lg) ? __expf(acl - se[3]) : 0.f;
            pk.x = (unsigned)f2bf(G[0] * w0) | ((unsigned)f2bf(G[1] * w1) << 16);
            pk.y = (unsigned)f2bf(G[2] * w2) | ((unsigned)f2bf(G[3] * w3) << 16);
          }
          *(uint2*)&Ps[wid][fr * 40 + 16 * ti + 4 * g] = pk;
        } else {
          uint2 zz; zz.x = 0u; zz.y = 0u;
          *(uint2*)&Ps[wid][fr * 40 + 16 * ti + 4 * g] = zz;
        }
      }
      const bf16x8 pf = *(const bf16x8*)&Ps[wid][fr * 40 + 8 * g];
      const bf16x8 xf = *(const bf16x8*)&xsT[fr * 264 + sp * 32 + 8 * g];
      acc = __builtin_amdgcn_mfma_f32_16x16x32_bf16(xf, pf, acc, 0, 0, 0);
    }
    // lane holds Y[l=lt*16+fr][p=4g+jr], jr=0..3 contiguous -> float4 store
    float4 o; o.x = acc[0]; o.y = acc[1]; o.z = acc[2]; o.w = acc[3];
    *(float4*)(Ydiag + ((size_t)b * SEQLEN + (size_t)cidx * CHUNK + lt * 16 + fr) * D_INNER
               + h * HEADDIM + 4 * g) = o;
  }

  __syncthreads();
  // ---- reduce partial states across waves, write stloc [p][n] ----
  {
    float s = sred[l] + sred[256 + l] + sred[512 + l] + sred[768 + l];
    stloc[((size_t)(b * NCHUNKS + cidx) * NHEADS + h) * 256 + l] = s;
  }
}

// ---------------------------------------------------------------------------
// K4: sequential inter-chunk state recurrence (layout-agnostic, [p][n])
// ---------------------------------------------------------------------------
__global__ __launch_bounds__(256)
void chunk_scan_kernel(const float* __restrict__ stloc, const float* __restrict__ csum_g,
                       float* __restrict__ stpre) {
  const int b  = blockIdx.x / NHEADS;
  const int h  = blockIdx.x % NHEADS;
  const int pn = threadIdx.x;
  float S = 0.0f;
  for (int c = 0; c < NCHUNKS; ++c) {
    const size_t idx = ((size_t)(b * NCHUNKS + c) * NHEADS + h) * 256 + pn;
    stpre[idx] = S;
    S = __expf(csum_g[(b * NHEADS + h) * NCHUNKS + c]) * S + stloc[idx];
  }
}

// ---------------------------------------------------------------------------
// K5: Y_off + D*x, silu(z) gate, RMSNorm (in-place into Yd)
// ---------------------------------------------------------------------------
__global__ __launch_bounds__(384)
void yoff_norm_kernel(float* __restrict__ Yd, const float* __restrict__ xo,
                      const float* __restrict__ Co, const float* __restrict__ acum_g,
                      const float* __restrict__ stpre, const float* __restrict__ Dvec,
                      const float* __restrict__ zxbdt, const float* __restrict__ norm_w) {
  const int row  = blockIdx.x;
  const int b    = row / SEQLEN, t = row % SEQLEN;
  const int cidx = t / CHUNK;
  const int d    = threadIdx.x;
  const int h    = d >> 4, p = d & 15;

  __shared__ float Cl[16];
  __shared__ float red[6];
  if (d < 16) Cl[d] = Co[(size_t)row * D_STATE + d];
  __syncthreads();

  const float* S = stpre + ((size_t)(b * NCHUNKS + cidx) * NHEADS + h) * 256 + p * 16;
  float dot = 0.0f;
#pragma unroll
  for (int n = 0; n < 16; ++n) dot += Cl[n] * S[n];
  const float acl = acum_g[(size_t)(b * NHEADS + h) * SEQLEN + t];
  float y = Yd[(size_t)row * D_INNER + d] + __expf(acl) * dot
          + Dvec[h] * xo[(size_t)row * D_INNER + d];
  const float z = zxbdt[(size_t)row * D_IN_PROJ + d];
  const float yg = y * silu_f(z);

  float v = yg * yg;
#pragma unroll
  for (int off = 32; off > 0; off >>= 1) v += __shfl_down(v, off);
  if ((d & 63) == 0) red[d >> 6] = v;
  __syncthreads();
  const float tot = red[0] + red[1] + red[2] + red[3] + red[4] + red[5];
  const float scale = rsqrtf(tot * (1.0f / D_INNER) + EPS);
  Yd[(size_t)row * D_INNER + d] = yg * scale * norm_w[d];
}

// ---------------------------------------------------------------------------
extern "C" void kernel_launch(void* const* d_in, const int* in_sizes, int n_in,
                              void* d_out, int out_size, void* d_ws, size_t ws_size,
                              hipStream_t stream) {
  const float* u        = (const float*)d_in[0];
  const float* support  = (const float*)d_in[1];
  const float* W_in     = (const float*)d_in[2];
  const float* W_in_b   = (const float*)d_in[3];
  const float* conv_w   = (const float*)d_in[4];
  const float* conv_b   = (const float*)d_in[5];
  const float* conv_w_b = (const float*)d_in[6];
  const float* conv_b_b = (const float*)d_in[7];
  const float* dt_bias  = (const float*)d_in[8];
  const float* A_log    = (const float*)d_in[9];
  const float* Dvec     = (const float*)d_in[10];
  const float* norm_w   = (const float*)d_in[11];
  const float* W_out    = (const float*)d_in[12];
  float* out = (float*)d_out;
  float* ws  = (float*)d_ws;

  float* zxbdt = ws;
  float* cproj = zxbdt + (size_t)ROWS * D_IN_PROJ;
  float* xo    = cproj + (size_t)ROWS * D_STATE;
  float* Bo    = xo    + (size_t)ROWS * D_INNER;
  float* Co    = Bo    + (size_t)ROWS * D_STATE;
  float* dto   = Co    + (size_t)ROWS * D_STATE;
  float* acum  = dto   + (size_t)ROWS * NHEADS;
  float* csum  = acum  + (size_t)BATCH * NHEADS * SEQLEN;
  float* stloc = csum  + (size_t)BATCH * NHEADS * NCHUNKS;
  float* stpre = stloc + (size_t)BATCH * NCHUNKS * NHEADS * 256;
  float* Yd    = stpre + (size_t)BATCH * NCHUNKS * NHEADS * 256;

  gemm_mfma<false><<<dim3((D_IN_PROJ + 63) / 64, ROWS / 128), 256, 0, stream>>>(
      u, W_in, zxbdt, ROWS, D_IN_PROJ, D_MODEL);
  gemm_nt<64, 16, 16, 4, 1><<<dim3(1, ROWS / 64), 256, 0, stream>>>(
      support, W_in_b, cproj, ROWS, D_STATE, D_MODEL);
  conv_dt_kernel<<<ROWS, 448, 0, stream>>>(zxbdt, cproj, conv_w, conv_b, conv_w_b,
                                           conv_b_b, dt_bias, xo, Bo, Co, dto);
  ssd_mfma_kernel<<<dim3(NHEADS, NCHUNKS, BATCH), 256, 0, stream>>>(
      xo, Bo, Co, dto, A_log, Yd, acum, csum, stloc);
  chunk_scan_kernel<<<BATCH * NHEADS, 256, 0, stream>>>(stloc, csum, stpre);
  yoff_norm_kernel<<<ROWS, 384, 0, stream>>>(Yd, xo, Co, acum, stpre, Dvec, zxbdt, norm_w);
  gemm_mfma<false><<<dim3(D_MODEL / 64, ROWS / 128), 256, 0, stream>>>(
      Yd, W_out, out, ROWS, D_MODEL, D_INNER);
}

// Round 4
// 180.156 us; speedup vs baseline: 2.1547x; 1.1050x over previous
//
#include <hip/hip_runtime.h>
#include <cmath>

#define ROWS      16384
#define SEQLEN    8192
#define BATCH     2
#define NHEADS    24
#define HEADDIM   16
#define D_STATE   16
#define D_INNER   384
#define D_MODEL   192
#define D_IN_PROJ 808
#define CONV_DIM  400
#define NCHUNKS   32
#define CHUNK     256
#define EPS       1e-5f

typedef short bf16x8 __attribute__((ext_vector_type(8)));
typedef float f32x4  __attribute__((ext_vector_type(4)));
typedef unsigned short us4v __attribute__((ext_vector_type(4)));
typedef unsigned short us8v __attribute__((ext_vector_type(8)));

__device__ __forceinline__ float silu_f(float x) { return x / (1.0f + expf(-x)); }
__device__ __forceinline__ float softplus_f(float x) { return (x > 20.0f) ? x : log1pf(expf(x)); }
__device__ __forceinline__ unsigned short f2bf(float x) {
  unsigned u = __builtin_bit_cast(unsigned, x);
  u += 0x7fff + ((u >> 16) & 1);
  return (unsigned short)(u >> 16);
}
__device__ __forceinline__ float bf2f(unsigned short s) {
  unsigned u = (unsigned)s << 16;
  return __builtin_bit_cast(float, u);
}

// ---------------------------------------------------------------------------
// K0: fp32 -> bf16 conversion for u, W_in, W_out (one launch)
// ---------------------------------------------------------------------------
__global__ __launch_bounds__(256)
void cvt3_kernel(const float* __restrict__ a, unsigned short* __restrict__ ao, long na,
                 const float* __restrict__ b, unsigned short* __restrict__ bo, long nb,
                 const float* __restrict__ c, unsigned short* __restrict__ co, long nc) {
  const long t0 = na >> 2, t1 = t0 + (nb >> 2), t2 = t1 + (nc >> 2);
  const long stride = (long)gridDim.x * blockDim.x;
  for (long i = (long)blockIdx.x * blockDim.x + threadIdx.x; i < t2; i += stride) {
    const float4* s; us4v* d; long j;
    if (i < t0)      { s = (const float4*)a; d = (us4v*)ao; j = i; }
    else if (i < t1) { s = (const float4*)b; d = (us4v*)bo; j = i - t0; }
    else             { s = (const float4*)c; d = (us4v*)co; j = i - t1; }
    float4 v = s[j];
    us4v o = { f2bf(v.x), f2bf(v.y), f2bf(v.z), f2bf(v.w) };
    d[j] = o;
  }
}

// ---------------------------------------------------------------------------
// MFMA bf16 GEMM: C[M,N] = A[M,K] * W[N,K]^T, A/W bf16, out fp32 or bf16.
// BM=128 BN=128 BK=32, 4 waves (2x2, wave tile 64x64), LDS double-buffered,
// one barrier per K-step, prefetch of step k+1 issued before MFMAs.
// ---------------------------------------------------------------------------
template<bool OUT_BF16>
__launch_bounds__(256, 3)
__global__ void gemm_bf16(const unsigned short* __restrict__ A,
                          const unsigned short* __restrict__ W,
                          void* __restrict__ Cp, int M, int N, int K) {
  constexpr int BM = 128, BN = 128, BK = 32, LDK = 40;
  __shared__ unsigned short As[2][BM * LDK];
  __shared__ unsigned short Ws[2][BN * LDK];
  const int tid  = threadIdx.x;
  const int wid  = tid >> 6, lane = tid & 63;
  const int wr   = wid >> 1, wc = wid & 1;
  const int fr   = lane & 15, fq = lane >> 4;
  const long m0  = (long)blockIdx.y * BM;
  const int  n0  = blockIdx.x * BN;

  f32x4 acc[4][4] = {};

  auto stage = [&](int k0, int buf) {
#pragma unroll
    for (int p = 0; p < 2; ++p) {
      int flat = p * 2048 + tid * 8;
      int r = flat >> 5, c = flat & 31;
      us8v v = *(const us8v*)(A + (m0 + r) * (long)K + k0 + c);
      *(us8v*)&As[buf][r * LDK + c] = v;
    }
#pragma unroll
    for (int p = 0; p < 2; ++p) {
      int flat = p * 2048 + tid * 8;
      int r = flat >> 5, c = flat & 31;
      int gn = n0 + r;
      us8v v = { 0, 0, 0, 0, 0, 0, 0, 0 };
      if (gn < N) v = *(const us8v*)(W + (long)gn * K + k0 + c);
      *(us8v*)&Ws[buf][r * LDK + c] = v;
    }
  };

  const int nk = K / BK;
  stage(0, 0);
  __syncthreads();
  for (int kt = 0; kt < nk; ++kt) {
    const int cur = kt & 1;
    if (kt + 1 < nk) stage((kt + 1) * BK, cur ^ 1);
    bf16x8 af[4], bfr[4];
#pragma unroll
    for (int m = 0; m < 4; ++m)
      af[m] = *(const bf16x8*)&As[cur][(wr * 64 + m * 16 + fr) * LDK + fq * 8];
#pragma unroll
    for (int n = 0; n < 4; ++n)
      bfr[n] = *(const bf16x8*)&Ws[cur][(wc * 64 + n * 16 + fr) * LDK + fq * 8];
#pragma unroll
    for (int m = 0; m < 4; ++m)
#pragma unroll
      for (int n = 0; n < 4; ++n)
        acc[m][n] = __builtin_amdgcn_mfma_f32_16x16x32_bf16(af[m], bfr[n], acc[m][n], 0, 0, 0);
    __syncthreads();
  }

#pragma unroll
  for (int m = 0; m < 4; ++m)
#pragma unroll
    for (int n = 0; n < 4; ++n)
#pragma unroll
      for (int j = 0; j < 4; ++j) {
        long gm = m0 + wr * 64 + m * 16 + fq * 4 + j;
        int  gn = n0 + wc * 64 + n * 16 + fr;
        if (gn < N) {
          if (OUT_BF16) ((unsigned short*)Cp)[gm * N + gn] = f2bf(acc[m][n][j]);
          else          ((float*)Cp)[gm * N + gn] = acc[m][n][j];
        }
      }
}

// ---------------------------------------------------------------------------
// fp32 SIMT GEMM (tiny K1b only: N=16)
// ---------------------------------------------------------------------------
template<int BM, int BN, int BK, int TM, int TN>
__launch_bounds__((BM / TM) * (BN / TN))
__global__ void gemm_nt(const float* __restrict__ A, const float* __restrict__ W,
                        float* __restrict__ C, int M, int N, int K) {
  __shared__ float As[BK][BM + 4];
  __shared__ float Ws[BK][BN + 4];
  constexpr int NTX = BN / TN;
  constexpr int NT  = (BM / TM) * (BN / TN);
  const int tid = threadIdx.x;
  const int tx  = tid % NTX;
  const int ty  = tid / NTX;
  const long m0 = (long)blockIdx.y * BM;
  const long n0 = (long)blockIdx.x * BN;
  float acc[TM][TN] = {};

  for (int k0 = 0; k0 < K; k0 += BK) {
    for (int i = tid; i < BM * BK; i += NT) {
      int m = i / BK, kk = i % BK;
      long gm = m0 + m;
      As[kk][m] = (gm < M) ? A[gm * K + (k0 + kk)] : 0.0f;
    }
    for (int i = tid; i < BN * BK; i += NT) {
      int n = i / BK, kk = i % BK;
      long gn = n0 + n;
      Ws[kk][n] = (gn < N) ? W[gn * K + (k0 + kk)] : 0.0f;
    }
    __syncthreads();
#pragma unroll
    for (int kk = 0; kk < BK; ++kk) {
      float a[TM], w[TN];
#pragma unroll
      for (int i = 0; i < TM; ++i) a[i] = As[kk][ty * TM + i];
#pragma unroll
      for (int j = 0; j < TN; ++j) w[j] = Ws[kk][tx * TN + j];
#pragma unroll
      for (int i = 0; i < TM; ++i)
#pragma unroll
        for (int j = 0; j < TN; ++j)
          acc[i][j] += a[i] * w[j];
    }
    __syncthreads();
  }
#pragma unroll
  for (int i = 0; i < TM; ++i) {
    long gm = m0 + ty * TM + i;
    if (gm >= M) continue;
#pragma unroll
    for (int j = 0; j < TN; ++j) {
      long gn = n0 + tx * TN + j;
      if (gn < N) C[gm * N + gn] = acc[i][j];
    }
  }
}

// ---------------------------------------------------------------------------
// K2: depthwise causal conv (width 4) + silu + dt softplus. bf16 in/out.
// ---------------------------------------------------------------------------
__global__ __launch_bounds__(448)
void conv_dt_kernel(const unsigned short* __restrict__ zxbdt, const float* __restrict__ cproj,
                    const float* __restrict__ conv_w, const float* __restrict__ conv_b,
                    const float* __restrict__ conv_w_b, const float* __restrict__ conv_b_b,
                    const float* __restrict__ dt_bias,
                    unsigned short* __restrict__ xo, unsigned short* __restrict__ Bo,
                    unsigned short* __restrict__ Co, float* __restrict__ dto) {
  const int row = blockIdx.x;
  const int t   = row % SEQLEN;
  const int c   = threadIdx.x;

  if (c < CONV_DIM) {
    const float w0 = conv_w[c * 4 + 0], w1 = conv_w[c * 4 + 1];
    const float w2 = conv_w[c * 4 + 2], w3 = conv_w[c * 4 + 3];
    const unsigned short* base = zxbdt + (size_t)row * D_IN_PROJ + D_INNER + c;
    const float x0 = (t >= 3) ? bf2f(base[-3 * D_IN_PROJ]) : 0.0f;
    const float x1 = (t >= 2) ? bf2f(base[-2 * D_IN_PROJ]) : 0.0f;
    const float x2 = (t >= 1) ? bf2f(base[-1 * D_IN_PROJ]) : 0.0f;
    const float x3 = bf2f(base[0]);
    float acc = conv_b[c] + w0 * x0 + w1 * x1 + w2 * x2 + w3 * x3;
    unsigned short y = f2bf(silu_f(acc));
    if (c < D_INNER) xo[(size_t)row * D_INNER + c] = y;
    else             Bo[(size_t)row * D_STATE + (c - D_INNER)] = y;
  } else if (c < CONV_DIM + D_STATE) {
    const int cc = c - CONV_DIM;
    const float w0 = conv_w_b[cc * 4 + 0], w1 = conv_w_b[cc * 4 + 1];
    const float w2 = conv_w_b[cc * 4 + 2], w3 = conv_w_b[cc * 4 + 3];
    const float* base = cproj + (size_t)row * D_STATE + cc;
    const float x0 = (t >= 3) ? base[-3 * D_STATE] : 0.0f;
    const float x1 = (t >= 2) ? base[-2 * D_STATE] : 0.0f;
    const float x2 = (t >= 1) ? base[-1 * D_STATE] : 0.0f;
    const float x3 = base[0];
    float acc = conv_b_b[cc] + w0 * x0 + w1 * x1 + w2 * x2 + w3 * x3;
    Co[(size_t)row * D_STATE + cc] = f2bf(silu_f(acc));
  } else if (c < CONV_DIM + D_STATE + NHEADS) {
    const int h = c - CONV_DIM - D_STATE;
    float v = bf2f(zxbdt[(size_t)row * D_IN_PROJ + (D_IN_PROJ - NHEADS) + h]) + dt_bias[h];
    dto[(size_t)row * NHEADS + h] = softplus_f(v);
  }
}

// ---------------------------------------------------------------------------
// K3 (MFMA): per (h, chunk, b) block, 4 waves. bf16 inputs, bf16 Yd out.
// Shuffle-based cumsum (3 barriers total).
// ---------------------------------------------------------------------------
__global__ __launch_bounds__(256, 2)
void ssd_mfma_kernel(const unsigned short* __restrict__ xo, const unsigned short* __restrict__ Bo,
                     const unsigned short* __restrict__ Co, const float* __restrict__ dto,
                     const float* __restrict__ A_log,
                     unsigned short* __restrict__ Ydiag, float* __restrict__ acum_g,
                     float* __restrict__ csum_g, float* __restrict__ stloc) {
  const int h    = blockIdx.x;
  const int cidx = blockIdx.y;
  const int b    = blockIdx.z;
  const int l    = threadIdx.x;
  const int t    = cidx * CHUNK + l;
  const size_t row = (size_t)b * SEQLEN + t;
  const int wid = l >> 6, lane = l & 63;
  const int fr  = lane & 15, g = lane >> 4;

  __shared__ unsigned short Bs[256 * 24 + 32];
  __shared__ unsigned short Cs[256 * 40];
  __shared__ unsigned short xsT[16 * 264];
  __shared__ unsigned short BwT[16 * 264];
  __shared__ unsigned short Ps[4][16 * 40];
  __shared__ float sc[CHUNK];
  __shared__ float sred[4 * 256];
  __shared__ float wsum[4];

  const float Ah  = -expf(A_log[h]);
  const float dtv = dto[row * NHEADS + h];

  // ---- wave-level inclusive scan of a = dt*A ----
  float v = dtv * Ah;
#pragma unroll
  for (int off = 1; off < 64; off <<= 1) {
    float u = __shfl_up(v, off, 64);
    if (lane >= off) v += u;
  }
  if (lane == 63) wsum[wid] = v;

  // ---- stage B, C, xdt (thread l owns chunk row l) ----
  us8v b0, b1;
  {
    const us8v z8 = { 0, 0, 0, 0, 0, 0, 0, 0 };
    const us8v* bp = (const us8v*)(Bo + row * D_STATE);
    b0 = bp[0]; b1 = bp[1];
    *(us8v*)&Bs[l * 24 + 0] = b0;
    *(us8v*)&Bs[l * 24 + 8] = b1;
    *(us8v*)&Bs[l * 24 + 16] = z8;
    if (l < 32) Bs[256 * 24 + l] = 0;
    const us8v* cp = (const us8v*)(Co + row * D_STATE);
    *(us8v*)&Cs[l * 40 + 0]  = cp[0];
    *(us8v*)&Cs[l * 40 + 8]  = cp[1];
    *(us8v*)&Cs[l * 40 + 16] = z8;
    *(us8v*)&Cs[l * 40 + 24] = z8;
    const us8v* xp = (const us8v*)(xo + row * D_INNER + h * HEADDIM);
    us8v x0 = xp[0], x1 = xp[1];
#pragma unroll
    for (int q = 0; q < 8; ++q) {
      xsT[q * 264 + l]       = f2bf(bf2f(x0[q]) * dtv);
      xsT[(q + 8) * 264 + l] = f2bf(bf2f(x1[q]) * dtv);
    }
  }
  __syncthreads();   // #1: wsum + staging visible

  // ---- cross-wave combine; write sc, acum, BwT ----
  float pre = 0.f, ctot = 0.f;
#pragma unroll
  for (int w = 0; w < 4; ++w) {
    float s = wsum[w];
    if (w < wid) pre += s;
    ctot += s;
  }
  v += pre;
  sc[l] = v;
  acum_g[(size_t)(b * NHEADS + h) * SEQLEN + t] = v;
  if (l == CHUNK - 1) csum_g[(b * NHEADS + h) * NCHUNKS + cidx] = v;
  const float wdv = __expf(ctot - v);
#pragma unroll
  for (int q = 0; q < 8; ++q) {
    BwT[q * 264 + l]       = f2bf(bf2f(b0[q]) * wdv);
    BwT[(q + 8) * 264 + l] = f2bf(bf2f(b1[q]) * wdv);
  }
  __syncthreads();   // #2

  // ---- chunk state: D[n][p], K=256 split across 4 waves ----
  {
    f32x4 accS = {};
    const int s0 = wid * 64;
#pragma unroll
    for (int k2 = 0; k2 < 2; ++k2) {
      bf16x8 af = *(const bf16x8*)&BwT[fr * 264 + s0 + 32 * k2 + 8 * g];
      bf16x8 bb = *(const bf16x8*)&xsT[fr * 264 + s0 + 32 * k2 + 8 * g];
      accS = __builtin_amdgcn_mfma_f32_16x16x32_bf16(af, bb, accS, 0, 0, 0);
    }
    *(f32x4*)&sred[wid * 256 + fr * 16 + 4 * g] = accS;
  }

  // ---- Y_diag: strips {wid,7-wid,8+wid,15-wid} ----
  const int strips[4] = { wid, 7 - wid, 8 + wid, 15 - wid };
  const f32x4 zf = { 0.f, 0.f, 0.f, 0.f };
#pragma unroll
  for (int q = 0; q < 4; ++q) {
    const int lt = strips[q];
    f32x4 acc = zf;
    const bf16x8 cf = *(const bf16x8*)&Cs[(lt * 16 + fr) * 40 + 8 * g];
    const float acl = sc[lt * 16 + fr];
    const int   lg  = lt * 16 + fr;
    const int npair = (lt + 2) >> 1;
    for (int sp = 0; sp < npair; ++sp) {
#pragma unroll
      for (int ti = 0; ti < 2; ++ti) {
        const int st = 2 * sp + ti;
        if (st <= lt) {
          bf16x8 bfg = *(const bf16x8*)&Bs[(st * 16 + fr) * 24 + 8 * g];
          f32x4 G = __builtin_amdgcn_mfma_f32_16x16x32_bf16(bfg, cf, zf, 0, 0, 0);
          f32x4 se = *(const f32x4*)&sc[st * 16 + 4 * g];
          uint2 pk;
          {
            const int sbase = st * 16 + 4 * g;
            float w0 = (sbase + 0 <= lg) ? __expf(acl - se[0]) : 0.f;
            float w1 = (sbase + 1 <= lg) ? __expf(acl - se[1]) : 0.f;
            float w2 = (sbase + 2 <= lg) ? __expf(acl - se[2]) : 0.f;
            float w3 = (sbase + 3 <= lg) ? __expf(acl - se[3]) : 0.f;
            pk.x = (unsigned)f2bf(G[0] * w0) | ((unsigned)f2bf(G[1] * w1) << 16);
            pk.y = (unsigned)f2bf(G[2] * w2) | ((unsigned)f2bf(G[3] * w3) << 16);
          }
          *(uint2*)&Ps[wid][fr * 40 + 16 * ti + 4 * g] = pk;
        } else {
          uint2 zz; zz.x = 0u; zz.y = 0u;
          *(uint2*)&Ps[wid][fr * 40 + 16 * ti + 4 * g] = zz;
        }
      }
      const bf16x8 pf = *(const bf16x8*)&Ps[wid][fr * 40 + 8 * g];
      const bf16x8 xf = *(const bf16x8*)&xsT[fr * 264 + sp * 32 + 8 * g];
      acc = __builtin_amdgcn_mfma_f32_16x16x32_bf16(xf, pf, acc, 0, 0, 0);
    }
    // lane holds Y[l=lt*16+fr][p=4g..4g+3] -> bf16 us4 store (8B)
    us4v o = { f2bf(acc[0]), f2bf(acc[1]), f2bf(acc[2]), f2bf(acc[3]) };
    *(us4v*)(Ydiag + ((size_t)b * SEQLEN + (size_t)cidx * CHUNK + lt * 16 + fr) * D_INNER
             + h * HEADDIM + 4 * g) = o;
  }

  __syncthreads();   // #3
  {
    float s = sred[l] + sred[256 + l] + sred[512 + l] + sred[768 + l];
    stloc[((size_t)(b * NCHUNKS + cidx) * NHEADS + h) * 256 + l] = s;
  }
}

// ---------------------------------------------------------------------------
// K4: sequential inter-chunk state recurrence ([p][n] layout)
// ---------------------------------------------------------------------------
__global__ __launch_bounds__(256)
void chunk_scan_kernel(const float* __restrict__ stloc, const float* __restrict__ csum_g,
                       float* __restrict__ stpre) {
  const int b  = blockIdx.x / NHEADS;
  const int h  = blockIdx.x % NHEADS;
  const int pn = threadIdx.x;
  float S = 0.0f;
  for (int c = 0; c < NCHUNKS; ++c) {
    const size_t idx = ((size_t)(b * NCHUNKS + c) * NHEADS + h) * 256 + pn;
    stpre[idx] = S;
    S = __expf(csum_g[(b * NHEADS + h) * NCHUNKS + c]) * S + stloc[idx];
  }
}

// ---------------------------------------------------------------------------
// K5: Y_off + D*x, silu(z) gate, RMSNorm (in-place into bf16 Yd)
// ---------------------------------------------------------------------------
__global__ __launch_bounds__(384)
void yoff_norm_kernel(unsigned short* __restrict__ Yd, const unsigned short* __restrict__ xo,
                      const unsigned short* __restrict__ Co, const float* __restrict__ acum_g,
                      const float* __restrict__ stpre, const float* __restrict__ Dvec,
                      const unsigned short* __restrict__ zxbdt, const float* __restrict__ norm_w) {
  const int row  = blockIdx.x;
  const int b    = row / SEQLEN, t = row % SEQLEN;
  const int cidx = t / CHUNK;
  const int d    = threadIdx.x;
  const int h    = d >> 4, p = d & 15;

  __shared__ float Cl[16];
  __shared__ float red[6];
  if (d < 16) Cl[d] = bf2f(Co[(size_t)row * D_STATE + d]);
  __syncthreads();

  const float* S = stpre + ((size_t)(b * NCHUNKS + cidx) * NHEADS + h) * 256 + p * 16;
  float dot = 0.0f;
#pragma unroll
  for (int n = 0; n < 16; ++n) dot += Cl[n] * S[n];
  const float acl = acum_g[(size_t)(b * NHEADS + h) * SEQLEN + t];
  float y = bf2f(Yd[(size_t)row * D_INNER + d]) + __expf(acl) * dot
          + Dvec[h] * bf2f(xo[(size_t)row * D_INNER + d]);
  const float z = bf2f(zxbdt[(size_t)row * D_IN_PROJ + d]);
  const float yg = y * silu_f(z);

  float v = yg * yg;
#pragma unroll
  for (int off = 32; off > 0; off >>= 1) v += __shfl_down(v, off);
  if ((d & 63) == 0) red[d >> 6] = v;
  __syncthreads();
  const float tot = red[0] + red[1] + red[2] + red[3] + red[4] + red[5];
  const float scale = rsqrtf(tot * (1.0f / D_INNER) + EPS);
  Yd[(size_t)row * D_INNER + d] = f2bf(yg * scale * norm_w[d]);
}

// ---------------------------------------------------------------------------
extern "C" void kernel_launch(void* const* d_in, const int* in_sizes, int n_in,
                              void* d_out, int out_size, void* d_ws, size_t ws_size,
                              hipStream_t stream) {
  const float* u        = (const float*)d_in[0];
  const float* support  = (const float*)d_in[1];
  const float* W_in     = (const float*)d_in[2];
  const float* W_in_b   = (const float*)d_in[3];
  const float* conv_w   = (const float*)d_in[4];
  const float* conv_b   = (const float*)d_in[5];
  const float* conv_w_b = (const float*)d_in[6];
  const float* conv_b_b = (const float*)d_in[7];
  const float* dt_bias  = (const float*)d_in[8];
  const float* A_log    = (const float*)d_in[9];
  const float* Dvec     = (const float*)d_in[10];
  const float* norm_w   = (const float*)d_in[11];
  const float* W_out    = (const float*)d_in[12];
  float* out = (float*)d_out;
  char* wsb  = (char*)d_ws;

  // workspace layout (byte offsets, 16B aligned)
  unsigned short* u_b    = (unsigned short*)(wsb);                         // 16384*192*2
  unsigned short* Wi_b   = u_b  + (size_t)ROWS * D_MODEL;                  // 808*192*2
  unsigned short* Wo_b   = Wi_b + (size_t)D_IN_PROJ * D_MODEL;             // 192*384*2
  unsigned short* zxbdt  = Wo_b + (size_t)D_MODEL * D_INNER;               // 16384*808*2
  unsigned short* xo     = zxbdt + (size_t)ROWS * D_IN_PROJ;               // 16384*384*2
  unsigned short* Bo     = xo + (size_t)ROWS * D_INNER;                    // 16384*16*2
  unsigned short* Co     = Bo + (size_t)ROWS * D_STATE;                    // 16384*16*2
  unsigned short* Yd     = Co + (size_t)ROWS * D_STATE;                    // 16384*384*2
  float* cproj = (float*)(Yd + (size_t)ROWS * D_INNER);                    // 16384*16*4
  float* dto   = cproj + (size_t)ROWS * D_STATE;                           // 16384*24*4
  float* acum  = dto   + (size_t)ROWS * NHEADS;                            // 2*24*8192*4
  float* csum  = acum  + (size_t)BATCH * NHEADS * SEQLEN;                  // 2*24*32
  float* stloc = csum  + (size_t)BATCH * NHEADS * NCHUNKS;                 // 2*32*24*256
  float* stpre = stloc + (size_t)BATCH * NCHUNKS * NHEADS * 256;

  // K0: convert u, W_in, W_out to bf16
  cvt3_kernel<<<2048, 256, 0, stream>>>(u, u_b, (long)ROWS * D_MODEL,
                                        W_in, Wi_b, (long)D_IN_PROJ * D_MODEL,
                                        W_out, Wo_b, (long)D_MODEL * D_INNER);
  // K1a: zxbdt = u @ W_in^T  (bf16 MFMA, bf16 out)
  gemm_bf16<true><<<dim3((D_IN_PROJ + 127) / 128, ROWS / 128), 256, 0, stream>>>(
      u_b, Wi_b, zxbdt, ROWS, D_IN_PROJ, D_MODEL);
  // K1b: cproj = support @ W_in_b^T (tiny, fp32 SIMT)
  gemm_nt<64, 16, 16, 4, 1><<<dim3(1, ROWS / 64), 256, 0, stream>>>(
      support, W_in_b, cproj, ROWS, D_STATE, D_MODEL);
  // K2
  conv_dt_kernel<<<ROWS, 448, 0, stream>>>(zxbdt, cproj, conv_w, conv_b, conv_w_b,
                                           conv_b_b, dt_bias, xo, Bo, Co, dto);
  // K3
  ssd_mfma_kernel<<<dim3(NHEADS, NCHUNKS, BATCH), 256, 0, stream>>>(
      xo, Bo, Co, dto, A_log, Yd, acum, csum, stloc);
  // K4
  chunk_scan_kernel<<<BATCH * NHEADS, 256, 0, stream>>>(stloc, csum, stpre);
  // K5
  yoff_norm_kernel<<<ROWS, 384, 0, stream>>>(Yd, xo, Co, acum, stpre, Dvec, zxbdt, norm_w);
  // K6: out = yn @ W_out^T  (bf16 MFMA, fp32 out)
  gemm_bf16<false><<<dim3((D_MODEL + 127) / 128, ROWS / 128), 256, 0, stream>>>(
      Yd, Wo_b, out, ROWS, D_MODEL, D_INNER);
}

// Round 5
// 176.645 us; speedup vs baseline: 2.1975x; 1.0199x over previous
//
#include <hip/hip_runtime.h>
#include <cmath>

#define ROWS      16384
#define SEQLEN    8192
#define BATCH     2
#define NHEADS    24
#define HEADDIM   16
#define D_STATE   16
#define D_INNER   384
#define D_MODEL   192
#define D_IN_PROJ 808
#define CONV_DIM  400
#define NCHUNKS   32
#define CHUNK     256
#define EPS       1e-5f

typedef short bf16x8 __attribute__((ext_vector_type(8)));
typedef float f32x4  __attribute__((ext_vector_type(4)));
typedef unsigned short us4v __attribute__((ext_vector_type(4)));
typedef unsigned short us8v __attribute__((ext_vector_type(8)));

__device__ __forceinline__ float silu_f(float x) { return x / (1.0f + expf(-x)); }
__device__ __forceinline__ float softplus_f(float x) { return (x > 20.0f) ? x : log1pf(expf(x)); }
__device__ __forceinline__ unsigned short f2bf(float x) {
  unsigned u = __builtin_bit_cast(unsigned, x);
  u += 0x7fff + ((u >> 16) & 1);
  return (unsigned short)(u >> 16);
}
__device__ __forceinline__ float bf2f(unsigned short s) {
  unsigned u = (unsigned)s << 16;
  return __builtin_bit_cast(float, u);
}

// ---------------------------------------------------------------------------
// K0: fp32 -> bf16 conversion for u, W_in, W_out
// ---------------------------------------------------------------------------
__global__ __launch_bounds__(256)
void cvt3_kernel(const float* __restrict__ a, unsigned short* __restrict__ ao, long na,
                 const float* __restrict__ b, unsigned short* __restrict__ bo, long nb,
                 const float* __restrict__ c, unsigned short* __restrict__ co, long nc) {
  const long t0 = na >> 2, t1 = t0 + (nb >> 2), t2 = t1 + (nc >> 2);
  const long stride = (long)gridDim.x * blockDim.x;
  for (long i = (long)blockIdx.x * blockDim.x + threadIdx.x; i < t2; i += stride) {
    const float4* s; us4v* d; long j;
    if (i < t0)      { s = (const float4*)a; d = (us4v*)ao; j = i; }
    else if (i < t1) { s = (const float4*)b; d = (us4v*)bo; j = i - t0; }
    else             { s = (const float4*)c; d = (us4v*)co; j = i - t1; }
    float4 v = s[j];
    us4v o = { f2bf(v.x), f2bf(v.y), f2bf(v.z), f2bf(v.w) };
    d[j] = o;
  }
}

// ---------------------------------------------------------------------------
// MFMA bf16 GEMM: C[M,N] = A[M,K] * W[N,K]^T, double-buffered LDS
// ---------------------------------------------------------------------------
template<bool OUT_BF16>
__launch_bounds__(256, 3)
__global__ void gemm_bf16(const unsigned short* __restrict__ A,
                          const unsigned short* __restrict__ W,
                          void* __restrict__ Cp, int M, int N, int K) {
  constexpr int BM = 128, BN = 128, BK = 32, LDK = 40;
  __shared__ unsigned short As[2][BM * LDK];
  __shared__ unsigned short Ws[2][BN * LDK];
  const int tid  = threadIdx.x;
  const int wid  = tid >> 6, lane = tid & 63;
  const int wr   = wid >> 1, wc = wid & 1;
  const int fr   = lane & 15, fq = lane >> 4;
  const long m0  = (long)blockIdx.y * BM;
  const int  n0  = blockIdx.x * BN;

  f32x4 acc[4][4] = {};

  auto stage = [&](int k0, int buf) {
#pragma unroll
    for (int p = 0; p < 2; ++p) {
      int flat = p * 2048 + tid * 8;
      int r = flat >> 5, c = flat & 31;
      us8v v = *(const us8v*)(A + (m0 + r) * (long)K + k0 + c);
      *(us8v*)&As[buf][r * LDK + c] = v;
    }
#pragma unroll
    for (int p = 0; p < 2; ++p) {
      int flat = p * 2048 + tid * 8;
      int r = flat >> 5, c = flat & 31;
      int gn = n0 + r;
      us8v v = { 0, 0, 0, 0, 0, 0, 0, 0 };
      if (gn < N) v = *(const us8v*)(W + (long)gn * K + k0 + c);
      *(us8v*)&Ws[buf][r * LDK + c] = v;
    }
  };

  const int nk = K / BK;
  stage(0, 0);
  __syncthreads();
  for (int kt = 0; kt < nk; ++kt) {
    const int cur = kt & 1;
    if (kt + 1 < nk) stage((kt + 1) * BK, cur ^ 1);
    bf16x8 af[4], bfr[4];
#pragma unroll
    for (int m = 0; m < 4; ++m)
      af[m] = *(const bf16x8*)&As[cur][(wr * 64 + m * 16 + fr) * LDK + fq * 8];
#pragma unroll
    for (int n = 0; n < 4; ++n)
      bfr[n] = *(const bf16x8*)&Ws[cur][(wc * 64 + n * 16 + fr) * LDK + fq * 8];
#pragma unroll
    for (int m = 0; m < 4; ++m)
#pragma unroll
      for (int n = 0; n < 4; ++n)
        acc[m][n] = __builtin_amdgcn_mfma_f32_16x16x32_bf16(af[m], bfr[n], acc[m][n], 0, 0, 0);
    __syncthreads();
  }

#pragma unroll
  for (int m = 0; m < 4; ++m)
#pragma unroll
    for (int n = 0; n < 4; ++n)
#pragma unroll
      for (int j = 0; j < 4; ++j) {
        long gm = m0 + wr * 64 + m * 16 + fq * 4 + j;
        int  gn = n0 + wc * 64 + n * 16 + fr;
        if (gn < N) {
          if (OUT_BF16) ((unsigned short*)Cp)[gm * N + gn] = f2bf(acc[m][n][j]);
          else          ((float*)Cp)[gm * N + gn] = acc[m][n][j];
        }
      }
}

// ---------------------------------------------------------------------------
// fp32 SIMT GEMM (tiny K1b only: N=16)
// ---------------------------------------------------------------------------
template<int BM, int BN, int BK, int TM, int TN>
__launch_bounds__((BM / TM) * (BN / TN))
__global__ void gemm_nt(const float* __restrict__ A, const float* __restrict__ W,
                        float* __restrict__ C, int M, int N, int K) {
  __shared__ float As[BK][BM + 4];
  __shared__ float Ws[BK][BN + 4];
  constexpr int NTX = BN / TN;
  constexpr int NT  = (BM / TM) * (BN / TN);
  const int tid = threadIdx.x;
  const int tx  = tid % NTX;
  const int ty  = tid / NTX;
  const long m0 = (long)blockIdx.y * BM;
  const long n0 = (long)blockIdx.x * BN;
  float acc[TM][TN] = {};

  for (int k0 = 0; k0 < K; k0 += BK) {
    for (int i = tid; i < BM * BK; i += NT) {
      int m = i / BK, kk = i % BK;
      long gm = m0 + m;
      As[kk][m] = (gm < M) ? A[gm * K + (k0 + kk)] : 0.0f;
    }
    for (int i = tid; i < BN * BK; i += NT) {
      int n = i / BK, kk = i % BK;
      long gn = n0 + n;
      Ws[kk][n] = (gn < N) ? W[gn * K + (k0 + kk)] : 0.0f;
    }
    __syncthreads();
#pragma unroll
    for (int kk = 0; kk < BK; ++kk) {
      float a[TM], w[TN];
#pragma unroll
      for (int i = 0; i < TM; ++i) a[i] = As[kk][ty * TM + i];
#pragma unroll
      for (int j = 0; j < TN; ++j) w[j] = Ws[kk][tx * TN + j];
#pragma unroll
      for (int i = 0; i < TM; ++i)
#pragma unroll
        for (int j = 0; j < TN; ++j)
          acc[i][j] += a[i] * w[j];
    }
    __syncthreads();
  }
#pragma unroll
  for (int i = 0; i < TM; ++i) {
    long gm = m0 + ty * TM + i;
    if (gm >= M) continue;
#pragma unroll
    for (int j = 0; j < TN; ++j) {
      long gn = n0 + tx * TN + j;
      if (gn < N) C[gm * N + gn] = acc[i][j];
    }
  }
}

// ---------------------------------------------------------------------------
// K2: tiled depthwise causal conv + silu + dt softplus. 16 rows/block.
// Outputs in head-major layouts: xoT [b][h][t][16], dtoT [b][h][t].
// ---------------------------------------------------------------------------
__global__ __launch_bounds__(448)
void conv_dt_tiled(const unsigned short* __restrict__ zxbdt, const float* __restrict__ cproj,
                   const float* __restrict__ conv_w, const float* __restrict__ conv_b,
                   const float* __restrict__ conv_w_b, const float* __restrict__ conv_b_b,
                   const float* __restrict__ dt_bias,
                   unsigned short* __restrict__ xoT, unsigned short* __restrict__ Bo,
                   unsigned short* __restrict__ Co, float* __restrict__ dtoT) {
  const int tile = blockIdx.x;                 // ROWS/16 blocks
  const int b    = (tile * 16) / SEQLEN;
  const int tl0  = (tile * 16) % SEQLEN;       // local t of first output row
  const int c    = threadIdx.x;

  __shared__ unsigned short xb[19][408];
  __shared__ float cb[19][16];

  for (int i = c; i < 19 * 400; i += 448) {
    int r = i / 400, col = i % 400;
    int st = tl0 - 3 + r;
    unsigned short v = 0;
    if (st >= 0) v = zxbdt[((size_t)b * SEQLEN + st) * D_IN_PROJ + D_INNER + col];
    xb[r][col] = v;
  }
  for (int i = c; i < 19 * 16; i += 448) {
    int r = i / 16, col = i % 16;
    int st = tl0 - 3 + r;
    cb[r][col] = (st >= 0) ? cproj[((size_t)b * SEQLEN + st) * D_STATE + col] : 0.0f;
  }
  __syncthreads();

  if (c < CONV_DIM) {
    const float w0 = conv_w[c * 4 + 0], w1 = conv_w[c * 4 + 1];
    const float w2 = conv_w[c * 4 + 2], w3 = conv_w[c * 4 + 3];
    const float bias = conv_b[c];
    const int h = c >> 4, i = c & 15;
#pragma unroll
    for (int tt = 0; tt < 16; ++tt) {
      float acc = bias + w0 * bf2f(xb[tt][c]) + w1 * bf2f(xb[tt + 1][c])
                + w2 * bf2f(xb[tt + 2][c]) + w3 * bf2f(xb[tt + 3][c]);
      unsigned short y = f2bf(silu_f(acc));
      const int tloc = tl0 + tt;
      if (c < D_INNER)
        xoT[((size_t)(b * NHEADS + h) * SEQLEN + tloc) * HEADDIM + i] = y;
      else
        Bo[((size_t)b * SEQLEN + tloc) * D_STATE + (c - D_INNER)] = y;
    }
  } else if (c < CONV_DIM + D_STATE) {
    const int cc = c - CONV_DIM;
    const float w0 = conv_w_b[cc * 4 + 0], w1 = conv_w_b[cc * 4 + 1];
    const float w2 = conv_w_b[cc * 4 + 2], w3 = conv_w_b[cc * 4 + 3];
    const float bias = conv_b_b[cc];
#pragma unroll
    for (int tt = 0; tt < 16; ++tt) {
      float acc = bias + w0 * cb[tt][cc] + w1 * cb[tt + 1][cc]
                + w2 * cb[tt + 2][cc] + w3 * cb[tt + 3][cc];
      Co[((size_t)b * SEQLEN + tl0 + tt) * D_STATE + cc] = f2bf(silu_f(acc));
    }
  } else if (c < CONV_DIM + D_STATE + NHEADS) {
    const int h = c - CONV_DIM - D_STATE;
    const float bias = dt_bias[h];
#pragma unroll
    for (int tt = 0; tt < 16; ++tt) {
      const int tloc = tl0 + tt;
      float v = bf2f(zxbdt[((size_t)b * SEQLEN + tloc) * D_IN_PROJ + (D_IN_PROJ - NHEADS) + h]) + bias;
      dtoT[(size_t)(b * NHEADS + h) * SEQLEN + tloc] = softplus_f(v);
    }
  }
}

// ---------------------------------------------------------------------------
// K3 (MFMA): per (h, chunk, b) block, 4 waves. Head-major in/out.
// ---------------------------------------------------------------------------
__global__ __launch_bounds__(256, 2)
void ssd_mfma_kernel(const unsigned short* __restrict__ xoT, const unsigned short* __restrict__ Bo,
                     const unsigned short* __restrict__ Co, const float* __restrict__ dtoT,
                     const float* __restrict__ A_log,
                     unsigned short* __restrict__ YdT, float* __restrict__ acum_g,
                     float* __restrict__ csum_g, float* __restrict__ stloc) {
  const int h    = blockIdx.x;
  const int cidx = blockIdx.y;
  const int b    = blockIdx.z;
  const int l    = threadIdx.x;
  const int t    = cidx * CHUNK + l;
  const size_t row  = (size_t)b * SEQLEN + t;                      // for Bo/Co
  const size_t hrow = (size_t)(b * NHEADS + h) * SEQLEN + t;       // for xoT/dtoT/acum
  const int wid = l >> 6, lane = l & 63;
  const int fr  = lane & 15, g = lane >> 4;

  __shared__ unsigned short Bs[256 * 24 + 32];
  __shared__ unsigned short Cs[256 * 40];
  __shared__ unsigned short xsT[16 * 264];
  __shared__ unsigned short BwT[16 * 264];
  __shared__ unsigned short Ps[4][16 * 40];
  __shared__ float sc[CHUNK];
  __shared__ float sred[4 * 256];
  __shared__ float wsum[4];

  const float Ah  = -expf(A_log[h]);
  const float dtv = dtoT[hrow];

  // wave-level inclusive scan of a = dt*A
  float v = dtv * Ah;
#pragma unroll
  for (int off = 1; off < 64; off <<= 1) {
    float u = __shfl_up(v, off, 64);
    if (lane >= off) v += u;
  }
  if (lane == 63) wsum[wid] = v;

  // stage B, C, xdt
  us8v b0, b1;
  {
    const us8v z8 = { 0, 0, 0, 0, 0, 0, 0, 0 };
    const us8v* bp = (const us8v*)(Bo + row * D_STATE);
    b0 = bp[0]; b1 = bp[1];
    *(us8v*)&Bs[l * 24 + 0] = b0;
    *(us8v*)&Bs[l * 24 + 8] = b1;
    *(us8v*)&Bs[l * 24 + 16] = z8;
    if (l < 32) Bs[256 * 24 + l] = 0;
    const us8v* cp = (const us8v*)(Co + row * D_STATE);
    *(us8v*)&Cs[l * 40 + 0]  = cp[0];
    *(us8v*)&Cs[l * 40 + 8]  = cp[1];
    *(us8v*)&Cs[l * 40 + 16] = z8;
    *(us8v*)&Cs[l * 40 + 24] = z8;
    const us8v* xp = (const us8v*)(xoT + hrow * HEADDIM);
    us8v x0 = xp[0], x1 = xp[1];
#pragma unroll
    for (int q = 0; q < 8; ++q) {
      xsT[q * 264 + l]       = f2bf(bf2f(x0[q]) * dtv);
      xsT[(q + 8) * 264 + l] = f2bf(bf2f(x1[q]) * dtv);
    }
  }
  __syncthreads();   // #1

  float pre = 0.f, ctot = 0.f;
#pragma unroll
  for (int w = 0; w < 4; ++w) {
    float s = wsum[w];
    if (w < wid) pre += s;
    ctot += s;
  }
  v += pre;
  sc[l] = v;
  acum_g[hrow] = v;
  if (l == CHUNK - 1) csum_g[(b * NHEADS + h) * NCHUNKS + cidx] = v;
  const float wdv = __expf(ctot - v);
#pragma unroll
  for (int q = 0; q < 8; ++q) {
    BwT[q * 264 + l]       = f2bf(bf2f(b0[q]) * wdv);
    BwT[(q + 8) * 264 + l] = f2bf(bf2f(b1[q]) * wdv);
  }
  __syncthreads();   // #2

  // chunk state partials
  {
    f32x4 accS = {};
    const int s0 = wid * 64;
#pragma unroll
    for (int k2 = 0; k2 < 2; ++k2) {
      bf16x8 af = *(const bf16x8*)&BwT[fr * 264 + s0 + 32 * k2 + 8 * g];
      bf16x8 bb = *(const bf16x8*)&xsT[fr * 264 + s0 + 32 * k2 + 8 * g];
      accS = __builtin_amdgcn_mfma_f32_16x16x32_bf16(af, bb, accS, 0, 0, 0);
    }
    *(f32x4*)&sred[wid * 256 + fr * 16 + 4 * g] = accS;
  }

  // Y_diag strips
  const int strips[4] = { wid, 7 - wid, 8 + wid, 15 - wid };
  const f32x4 zf = { 0.f, 0.f, 0.f, 0.f };
#pragma unroll
  for (int q = 0; q < 4; ++q) {
    const int lt = strips[q];
    f32x4 acc = zf;
    const bf16x8 cf = *(const bf16x8*)&Cs[(lt * 16 + fr) * 40 + 8 * g];
    const float acl = sc[lt * 16 + fr];
    const int   lg  = lt * 16 + fr;
    const int npair = (lt + 2) >> 1;
    for (int sp = 0; sp < npair; ++sp) {
#pragma unroll
      for (int ti = 0; ti < 2; ++ti) {
        const int st = 2 * sp + ti;
        if (st <= lt) {
          bf16x8 bfg = *(const bf16x8*)&Bs[(st * 16 + fr) * 24 + 8 * g];
          f32x4 G = __builtin_amdgcn_mfma_f32_16x16x32_bf16(bfg, cf, zf, 0, 0, 0);
          f32x4 se = *(const f32x4*)&sc[st * 16 + 4 * g];
          uint2 pk;
          {
            const int sbase = st * 16 + 4 * g;
            float w0 = (sbase + 0 <= lg) ? __expf(acl - se[0]) : 0.f;
            float w1 = (sbase + 1 <= lg) ? __expf(acl - se[1]) : 0.f;
            float w2 = (sbase + 2 <= lg) ? __expf(acl - se[2]) : 0.f;
            float w3 = (sbase + 3 <= lg) ? __expf(acl - se[3]) : 0.f;
            pk.x = (unsigned)f2bf(G[0] * w0) | ((unsigned)f2bf(G[1] * w1) << 16);
            pk.y = (unsigned)f2bf(G[2] * w2) | ((unsigned)f2bf(G[3] * w3) << 16);
          }
          *(uint2*)&Ps[wid][fr * 40 + 16 * ti + 4 * g] = pk;
        } else {
          uint2 zz; zz.x = 0u; zz.y = 0u;
          *(uint2*)&Ps[wid][fr * 40 + 16 * ti + 4 * g] = zz;
        }
      }
      const bf16x8 pf = *(const bf16x8*)&Ps[wid][fr * 40 + 8 * g];
      const bf16x8 xf = *(const bf16x8*)&xsT[fr * 264 + sp * 32 + 8 * g];
      acc = __builtin_amdgcn_mfma_f32_16x16x32_bf16(xf, pf, acc, 0, 0, 0);
    }
    // store Y head-major: [(b*NH+h)*SEQLEN + t][p]
    us4v o = { f2bf(acc[0]), f2bf(acc[1]), f2bf(acc[2]), f2bf(acc[3]) };
    *(us4v*)(YdT + ((size_t)(b * NHEADS + h) * SEQLEN + (size_t)cidx * CHUNK + lt * 16 + fr) * HEADDIM
             + 4 * g) = o;
  }

  __syncthreads();   // #3
  {
    float s = sred[l] + sred[256 + l] + sred[512 + l] + sred[768 + l];
    stloc[((size_t)(b * NCHUNKS + cidx) * NHEADS + h) * 256 + l] = s;
  }
}

// ---------------------------------------------------------------------------
// K4: sequential inter-chunk state recurrence ([p][n] layout)
// ---------------------------------------------------------------------------
__global__ __launch_bounds__(256)
void chunk_scan_kernel(const float* __restrict__ stloc, const float* __restrict__ csum_g,
                       float* __restrict__ stpre) {
  const int b  = blockIdx.x / NHEADS;
  const int h  = blockIdx.x % NHEADS;
  const int pn = threadIdx.x;
  float S = 0.0f;
  for (int c = 0; c < NCHUNKS; ++c) {
    const size_t idx = ((size_t)(b * NCHUNKS + c) * NHEADS + h) * 256 + pn;
    stpre[idx] = S;
    S = __expf(csum_g[(b * NHEADS + h) * NCHUNKS + c]) * S + stloc[idx];
  }
}

// ---------------------------------------------------------------------------
// K5: Y_off + D*x, silu(z) gate, RMSNorm. Reads head-major YdT/xoT,
// writes row-major yn (bf16) for the out-proj GEMM.
// ---------------------------------------------------------------------------
__global__ __launch_bounds__(384)
void yoff_norm_kernel(const unsigned short* __restrict__ YdT, const unsigned short* __restrict__ xoT,
                      const unsigned short* __restrict__ Co, const float* __restrict__ acum_g,
                      const float* __restrict__ stpre, const float* __restrict__ Dvec,
                      const unsigned short* __restrict__ zxbdt, const float* __restrict__ norm_w,
                      unsigned short* __restrict__ yn) {
  const int row  = blockIdx.x;
  const int b    = row / SEQLEN, t = row % SEQLEN;
  const int cidx = t / CHUNK;
  const int d    = threadIdx.x;
  const int h    = d >> 4, p = d & 15;

  __shared__ float Cl[16];
  __shared__ float red[6];
  if (d < 16) Cl[d] = bf2f(Co[(size_t)row * D_STATE + d]);
  __syncthreads();

  const size_t hrow = (size_t)(b * NHEADS + h) * SEQLEN + t;
  const float* S = stpre + ((size_t)(b * NCHUNKS + cidx) * NHEADS + h) * 256 + p * 16;
  float dot = 0.0f;
#pragma unroll
  for (int n = 0; n < 16; ++n) dot += Cl[n] * S[n];
  const float acl = acum_g[hrow];
  float y = bf2f(YdT[hrow * HEADDIM + p]) + __expf(acl) * dot
          + Dvec[h] * bf2f(xoT[hrow * HEADDIM + p]);
  const float z = bf2f(zxbdt[(size_t)row * D_IN_PROJ + d]);
  const float yg = y * silu_f(z);

  float v = yg * yg;
#pragma unroll
  for (int off = 32; off > 0; off >>= 1) v += __shfl_down(v, off);
  if ((d & 63) == 0) red[d >> 6] = v;
  __syncthreads();
  const float tot = red[0] + red[1] + red[2] + red[3] + red[4] + red[5];
  const float scale = rsqrtf(tot * (1.0f / D_INNER) + EPS);
  yn[(size_t)row * D_INNER + d] = f2bf(yg * scale * norm_w[d]);
}

// ---------------------------------------------------------------------------
extern "C" void kernel_launch(void* const* d_in, const int* in_sizes, int n_in,
                              void* d_out, int out_size, void* d_ws, size_t ws_size,
                              hipStream_t stream) {
  const float* u        = (const float*)d_in[0];
  const float* support  = (const float*)d_in[1];
  const float* W_in     = (const float*)d_in[2];
  const float* W_in_b   = (const float*)d_in[3];
  const float* conv_w   = (const float*)d_in[4];
  const float* conv_b   = (const float*)d_in[5];
  const float* conv_w_b = (const float*)d_in[6];
  const float* conv_b_b = (const float*)d_in[7];
  const float* dt_bias  = (const float*)d_in[8];
  const float* A_log    = (const float*)d_in[9];
  const float* Dvec     = (const float*)d_in[10];
  const float* norm_w   = (const float*)d_in[11];
  const float* W_out    = (const float*)d_in[12];
  float* out = (float*)d_out;
  char* wsb  = (char*)d_ws;

  unsigned short* u_b   = (unsigned short*)(wsb);
  unsigned short* Wi_b  = u_b  + (size_t)ROWS * D_MODEL;
  unsigned short* Wo_b  = Wi_b + (size_t)D_IN_PROJ * D_MODEL;
  unsigned short* zxbdt = Wo_b + (size_t)D_MODEL * D_INNER;
  unsigned short* xoT   = zxbdt + (size_t)ROWS * D_IN_PROJ;      // [b][h][t][16]
  unsigned short* Bo    = xoT + (size_t)ROWS * D_INNER;          // [b][t][16]
  unsigned short* Co    = Bo + (size_t)ROWS * D_STATE;           // [b][t][16]
  unsigned short* YdT   = Co + (size_t)ROWS * D_STATE;           // [b][h][t][16]
  unsigned short* yn    = YdT + (size_t)ROWS * D_INNER;          // [row][384]
  float* cproj = (float*)(yn + (size_t)ROWS * D_INNER);
  float* dtoT  = cproj + (size_t)ROWS * D_STATE;                 // [b][h][t]
  float* acum  = dtoT  + (size_t)ROWS * NHEADS;                  // [b][h][t]
  float* csum  = acum  + (size_t)BATCH * NHEADS * SEQLEN;
  float* stloc = csum  + (size_t)BATCH * NHEADS * NCHUNKS;
  float* stpre = stloc + (size_t)BATCH * NCHUNKS * NHEADS * 256;

  cvt3_kernel<<<2048, 256, 0, stream>>>(u, u_b, (long)ROWS * D_MODEL,
                                        W_in, Wi_b, (long)D_IN_PROJ * D_MODEL,
                                        W_out, Wo_b, (long)D_MODEL * D_INNER);
  gemm_bf16<true><<<dim3((D_IN_PROJ + 127) / 128, ROWS / 128), 256, 0, stream>>>(
      u_b, Wi_b, zxbdt, ROWS, D_IN_PROJ, D_MODEL);
  gemm_nt<64, 16, 16, 4, 1><<<dim3(1, ROWS / 64), 256, 0, stream>>>(
      support, W_in_b, cproj, ROWS, D_STATE, D_MODEL);
  conv_dt_tiled<<<ROWS / 16, 448, 0, stream>>>(zxbdt, cproj, conv_w, conv_b, conv_w_b,
                                               conv_b_b, dt_bias, xoT, Bo, Co, dtoT);
  ssd_mfma_kernel<<<dim3(NHEADS, NCHUNKS, BATCH), 256, 0, stream>>>(
      xoT, Bo, Co, dtoT, A_log, YdT, acum, csum, stloc);
  chunk_scan_kernel<<<BATCH * NHEADS, 256, 0, stream>>>(stloc, csum, stpre);
  yoff_norm_kernel<<<ROWS, 384, 0, stream>>>(YdT, xoT, Co, acum, stpre, Dvec, zxbdt,
                                             norm_w, yn);
  gemm_bf16<false><<<dim3((D_MODEL + 127) / 128, ROWS / 128), 256, 0, stream>>>(
      yn, Wo_b, out, ROWS, D_MODEL, D_INNER);
}